// Round 5
// baseline (440.175 us; speedup 1.0000x reference)
//
#include <hip/hip_runtime.h>
#include <hip/hip_bf16.h>

#define S_LEN 2048
#define EMB   1024
#define NH    16
#define HD    64
#define FF_DIM 4096
#define BATCH 2

typedef __attribute__((ext_vector_type(8))) short bf16x8;
typedef __attribute__((ext_vector_type(4))) float f32x4;

__device__ __forceinline__ short f2bf(float x) {
  __hip_bfloat16 h = (__hip_bfloat16)x;
  return *(short*)&h;
}
__device__ __forceinline__ bf16x8 pack8(float4 a, float4 b) {
  bf16x8 o;
  o[0] = f2bf(a.x); o[1] = f2bf(a.y); o[2] = f2bf(a.z); o[3] = f2bf(a.w);
  o[4] = f2bf(b.x); o[5] = f2bf(b.y); o[6] = f2bf(b.z); o[7] = f2bf(b.w);
  return o;
}

// async global->LDS, 16B/lane; LDS dest = wave-uniform base + lane*16
__device__ __forceinline__ void gl2lds16(const void* g, void* l) {
  __builtin_amdgcn_global_load_lds(
      (const __attribute__((address_space(1))) unsigned*)g,
      (__attribute__((address_space(3))) unsigned*)l, 16, 0, 0);
}

// raw barrier WITHOUT the vmcnt(0) drain __syncthreads would emit.
__device__ __forceinline__ void bar() {
  asm volatile("" ::: "memory");
  __builtin_amdgcn_s_barrier();
  asm volatile("" ::: "memory");
}
#define WAITVM(n) asm volatile("s_waitcnt vmcnt(" #n ")" ::: "memory")
#define LGKM0     asm volatile("s_waitcnt lgkmcnt(0)" ::: "memory")

// ------------- fused fp32->bf16 convert+transpose for Wo, W1, W2 -------------
__device__ __forceinline__ void transpose_tile(
    const float* in, short* outS, int R, int C, int bx, int by, int t) {
  __shared__ short Ts[64][65];
  int cb = bx * 64, rb = by * 64;
  for (int idx = t; idx < 4096; idx += 256) {
    int r = idx >> 6, c = idx & 63;
    Ts[r][c] = f2bf(in[(size_t)(rb + r) * C + cb + c]);
  }
  __syncthreads();
  for (int idx = t; idx < 4096; idx += 256) {
    int oc = idx >> 6, orr = idx & 63;
    outS[(size_t)(cb + oc) * R + rb + orr] = Ts[orr][oc];
  }
}

__global__ __launch_bounds__(256) void transpose_all(
    const float* __restrict__ Wo, const float* __restrict__ W1,
    const float* __restrict__ W2, __hip_bfloat16* __restrict__ WoT,
    __hip_bfloat16* __restrict__ W1T, __hip_bfloat16* __restrict__ W2T) {
  int id = blockIdx.x, t = threadIdx.x;
  if (id < 256)        transpose_tile(Wo, (short*)WoT, EMB, EMB,    id & 15,          id >> 4,          t);
  else if (id < 1280)  transpose_tile(W1, (short*)W1T, EMB, FF_DIM, (id - 256) & 63,  (id - 256) >> 6,  t);
  else                 transpose_tile(W2, (short*)W2T, FF_DIM, EMB, (id - 1280) & 15, (id - 1280) >> 4, t);
}

// ---------------- xavg: zero + atomic partial sums (coalesced) ----------------
__global__ __launch_bounds__(256) void zero_f32(float* __restrict__ p) {
  p[blockIdx.x * 256 + threadIdx.x] = 0.f;
}

__global__ __launch_bounds__(256) void xavg_partial(
    const float* __restrict__ Q, float* __restrict__ xavg) {
  int b = blockIdx.y;
  int s0 = blockIdx.x * 16;
  int t = threadIdx.x;
  const float* base = Q + ((size_t)b * S_LEN + s0) * EMB + 4 * t;
  float4 acc = {0.f, 0.f, 0.f, 0.f};
#pragma unroll 4
  for (int r = 0; r < 16; r++) {
    float4 v = *(const float4*)(base + (size_t)r * EMB);
    acc.x += v.x; acc.y += v.y; acc.z += v.z; acc.w += v.w;
  }
  float* dst = xavg + b * EMB + 4 * t;
  const float inv = 1.f / (float)S_LEN;
  atomicAdd(dst + 0, acc.x * inv);
  atomicAdd(dst + 1, acc.y * inv);
  atomicAdd(dst + 2, acc.z * inv);
  atomicAdd(dst + 3, acc.w * inv);
}

// ---------------- gate = sigmoid(xavg @ Wg + bg) ----------------
__global__ __launch_bounds__(256) void gate_kernel(
    const float* __restrict__ xavg, const float* __restrict__ Wg,
    const float* __restrict__ bg, float* __restrict__ gate) {
  __shared__ float red[4][64];
  int b = blockIdx.y;
  int nl = threadIdx.x & 63;
  int n = blockIdx.x * 64 + nl;
  int kg = threadIdx.x >> 6;
  const float* xa = xavg + b * EMB;
  float s = 0.f;
#pragma unroll 4
  for (int k = kg * 256; k < kg * 256 + 256; k++)
    s += xa[k] * Wg[(size_t)k * EMB + n];
  red[kg][nl] = s;
  __syncthreads();
  if (kg == 0) {
    float tot = red[0][nl] + red[1][nl] + red[2][nl] + red[3][nl] + bg[n];
    gate[b * EMB + n] = 1.f / (1.f + __expf(-tot));
  }
}

// ---------------- pack K/V: fp32 [b,s,h*64] -> bf16 Kp[b,h,s,d], Vt[b,h,d,s] ----
__global__ __launch_bounds__(256) void pack_kv(
    const float* __restrict__ Kg, const float* __restrict__ Vg,
    __hip_bfloat16* __restrict__ Kp, __hip_bfloat16* __restrict__ Vt) {
  __shared__ short Vs[64][72];
  int s0 = blockIdx.x * 64, h = blockIdx.y, b = blockIdx.z;
  int t = threadIdx.x, r = t >> 2, c = (t & 3) * 16;
  size_t gin = ((size_t)b * S_LEN + s0 + r) * EMB + h * HD + c;
  {
    float4 a0 = *(const float4*)(Kg + gin);
    float4 a1 = *(const float4*)(Kg + gin + 4);
    float4 a2 = *(const float4*)(Kg + gin + 8);
    float4 a3 = *(const float4*)(Kg + gin + 12);
    short* kp = (short*)Kp + (((size_t)b * NH + h) * S_LEN + s0 + r) * HD + c;
    *(bf16x8*)(kp)     = pack8(a0, a1);
    *(bf16x8*)(kp + 8) = pack8(a2, a3);
  }
  {
    float4 a0 = *(const float4*)(Vg + gin);
    float4 a1 = *(const float4*)(Vg + gin + 4);
    float4 a2 = *(const float4*)(Vg + gin + 8);
    float4 a3 = *(const float4*)(Vg + gin + 12);
    *(bf16x8*)&Vs[r][c]     = pack8(a0, a1);
    *(bf16x8*)&Vs[r][c + 8] = pack8(a2, a3);
  }
  __syncthreads();
  bf16x8 o0, o1;
#pragma unroll
  for (int j = 0; j < 8; j++) o0[j] = Vs[c + j][r];
#pragma unroll
  for (int j = 0; j < 8; j++) o1[j] = Vs[c + 8 + j][r];
  short* vp = (short*)Vt + (((size_t)b * NH + h) * HD + r) * S_LEN + s0 + c;
  *(bf16x8*)(vp)     = o0;
  *(bf16x8*)(vp + 8) = o1;
}

// ---------------- causal flash attention, MFMA bf16 ----------------
__global__ __launch_bounds__(256) void flash_attn_mfma(
    const float* __restrict__ Q, const __hip_bfloat16* __restrict__ Kp,
    const __hip_bfloat16* __restrict__ Vtb, __hip_bfloat16* __restrict__ O) {
  __shared__ short Ks[64][72];
  __shared__ short Vt[64][72];
  __shared__ short Ps[4][16][72];  // bf16 P, per wave; row stride 144B (16B-mult)
  int t = threadIdx.x;
  int w = t >> 6, lane = t & 63, quad = lane >> 4, l15 = lane & 15;
  int j = blockIdx.x;
  int p = j & 255, g = j >> 8;
  int bh = p & 31, c_ = p >> 5;
  int qb = (g == 0) ? c_ : (g == 1) ? (15 - c_) : (g == 2) ? (16 + c_) : (31 - c_);
  int h = bh & 15, b = bh >> 4;
  size_t base = ((size_t)b * S_LEN) * EMB + h * HD;
  const short* kpb = (const short*)Kp + ((size_t)b * NH + h) * S_LEN * HD;
  const short* vtb = (const short*)Vtb + ((size_t)b * NH + h) * HD * S_LEN;

  // Q A-fragments, pre-scaled by 1/sqrt(HD)=0.125
  bf16x8 qf[2];
  {
    const float* qrow = Q + base + (size_t)(qb * 64 + w * 16 + l15) * EMB;
#pragma unroll
    for (int kc = 0; kc < 2; kc++) {
      float4 a = *(const float4*)(qrow + kc * 32 + quad * 8);
      float4 c = *(const float4*)(qrow + kc * 32 + quad * 8 + 4);
      a.x *= 0.125f; a.y *= 0.125f; a.z *= 0.125f; a.w *= 0.125f;
      c.x *= 0.125f; c.y *= 0.125f; c.z *= 0.125f; c.w *= 0.125f;
      qf[kc] = pack8(a, c);
    }
  }

  f32x4 acc[4];
  float lsum[4];
  f32x4 zero = {0.f, 0.f, 0.f, 0.f};
#pragma unroll
  for (int n = 0; n < 4; n++) acc[n] = zero;
#pragma unroll
  for (int r = 0; r < 4; r++) lsum[r] = 0.f;

  int r0 = t >> 2, c0 = (t & 3) * 16;
  bf16x8 kf0, kf1, vf0, vf1;  // prefetch regs
  {
    const short* kr = kpb + (size_t)r0 * HD + c0;
    kf0 = *(const bf16x8*)(kr); kf1 = *(const bf16x8*)(kr + 8);
    const short* vr = vtb + (size_t)r0 * S_LEN + c0;
    vf0 = *(const bf16x8*)(vr); vf1 = *(const bf16x8*)(vr + 8);
  }

  for (int kt = 0; kt <= qb; kt++) {
    __syncthreads();
    *(bf16x8*)&Ks[r0][c0]     = kf0;
    *(bf16x8*)&Ks[r0][c0 + 8] = kf1;
    *(bf16x8*)&Vt[r0][c0]     = vf0;
    *(bf16x8*)&Vt[r0][c0 + 8] = vf1;
    __syncthreads();
    if (kt < qb) {  // prefetch next tile during compute
      const short* kr = kpb + (size_t)((kt + 1) * 64 + r0) * HD + c0;
      kf0 = *(const bf16x8*)(kr); kf1 = *(const bf16x8*)(kr + 8);
      const short* vr = vtb + (size_t)r0 * S_LEN + (kt + 1) * 64 + c0;
      vf0 = *(const bf16x8*)(vr); vf1 = *(const bf16x8*)(vr + 8);
    }

    // S = (Q/8) K^T   (T5: boost wave priority through the MFMA cluster)
    f32x4 sc[4];
#pragma unroll
    for (int n = 0; n < 4; n++) sc[n] = zero;
    __builtin_amdgcn_s_setprio(1);
#pragma unroll
    for (int n = 0; n < 4; n++)
#pragma unroll
      for (int kc = 0; kc < 2; kc++) {
        bf16x8 kf = *(const bf16x8*)&Ks[n * 16 + l15][kc * 32 + quad * 8];
        sc[n] = __builtin_amdgcn_mfma_f32_16x16x32_bf16(qf[kc], kf, sc[n], 0, 0, 0);
      }
    __builtin_amdgcn_s_setprio(0);

    bool diag = (kt == qb);
#pragma unroll
    for (int r = 0; r < 4; r++) {
      float p0 = __expf(sc[0][r]);
      float p1 = __expf(sc[1][r]);
      float p2 = __expf(sc[2][r]);
      float p3 = __expf(sc[3][r]);
      if (diag) {
        int rowL = w * 16 + quad * 4 + r;
        if (l15      > rowL) p0 = 0.f;
        if (l15 + 16 > rowL) p1 = 0.f;
        if (l15 + 32 > rowL) p2 = 0.f;
        if (l15 + 48 > rowL) p3 = 0.f;
      }
      lsum[r] += (p0 + p1) + (p2 + p3);
      short* prow = &Ps[w][quad * 4 + r][l15];
      prow[0]  = f2bf(p0);
      prow[16] = f2bf(p1);
      prow[32] = f2bf(p2);
      prow[48] = f2bf(p3);
    }
    // drain same-wave DS writes before cross-lane reads (per-wave P region)
    asm volatile("s_waitcnt lgkmcnt(0)" ::: "memory");

    bf16x8 pf0 = *(const bf16x8*)&Ps[w][l15][quad * 8];
    bf16x8 pf1 = *(const bf16x8*)&Ps[w][l15][32 + quad * 8];
    __builtin_amdgcn_s_setprio(1);
#pragma unroll
    for (int n = 0; n < 4; n++) {
      bf16x8 vfa = *(const bf16x8*)&Vt[n * 16 + l15][quad * 8];
      acc[n] = __builtin_amdgcn_mfma_f32_16x16x32_bf16(pf0, vfa, acc[n], 0, 0, 0);
      bf16x8 vfb = *(const bf16x8*)&Vt[n * 16 + l15][32 + quad * 8];
      acc[n] = __builtin_amdgcn_mfma_f32_16x16x32_bf16(pf1, vfb, acc[n], 0, 0, 0);
    }
    __builtin_amdgcn_s_setprio(0);
  }

  // deferred row-sum: one shuffle reduction across the 16-lane row group
#pragma unroll
  for (int r = 0; r < 4; r++) {
    float l = lsum[r];
#pragma unroll
    for (int off = 1; off < 16; off <<= 1) l += __shfl_xor(l, off);
    float invl = 1.f / l;
    size_t orow = base + (size_t)(qb * 64 + w * 16 + quad * 4 + r) * EMB;
#pragma unroll
    for (int n = 0; n < 4; n++)
      O[orow + n * 16 + l15] = (__hip_bfloat16)(acc[n][r] * invl);
  }
}

// ======== 256x256 8-phase counted-vmcnt GEMM (T2+T3+T4+T5), MODE1 epilogue ====
#define MFMA_QUAD(MH, NHq)                                                       \
  __builtin_amdgcn_s_setprio(1);                                                 \
  _Pragma("unroll") for (int mi_ = 0; mi_ < 4; mi_++)                            \
  _Pragma("unroll") for (int ni_ = 0; ni_ < 2; ni_++)                            \
  _Pragma("unroll") for (int kh_ = 0; kh_ < 2; kh_++)                            \
    acc[(MH) * 4 + mi_][(NHq) * 2 + ni_] = __builtin_amdgcn_mfma_f32_16x16x32_bf16( \
        af[mi_][kh_], bfr[(NHq) * 2 + ni_][kh_], acc[(MH) * 4 + mi_][(NHq) * 2 + ni_], 0, 0, 0); \
  __builtin_amdgcn_s_setprio(0);

__global__ __launch_bounds__(512) void gemm8p_gelu(
    const __hip_bfloat16* __restrict__ A, const __hip_bfloat16* __restrict__ BT,
    int K, int N, const float* __restrict__ bias, __hip_bfloat16* __restrict__ outB) {
  __shared__ short As[2][256][64];
  __shared__ short Bs[2][256][64];
  int t = threadIdx.x;
  int w = t >> 6, lane = t & 63, quad = lane >> 4, l15 = lane & 15;
  int warp_m = w >> 2, warp_n = w & 3;
  // bijective XCD swizzle (gridDim.x % 8 == 0)
  int cpx = gridDim.x >> 3;
  int swz = ((int)blockIdx.x & 7) * cpx + ((int)blockIdx.x >> 3);
  int nbn = N >> 8;
  int mBase = (swz / nbn) << 8, nBase = (swz % nbn) << 8;
  const short* Ag = (const short*)A;
  const short* Bg = (const short*)BT;
  int sck = t & 7;          // storage chunk this lane stages
  int rr = t >> 3;          // 0..63 row within a 64-row staging round
  int wrow = w << 3;        // wave's dest row base within round

  auto stA = [&](int buf, int kt, int h) {
    int kb = kt << 6;
#pragma unroll
    for (int rd = 0; rd < 2; rd++) {
      int R = h * 128 + rd * 64 + rr;
      gl2lds16(&Ag[(size_t)(mBase + R) * K + kb + ((sck ^ (R & 7)) << 3)],
               &As[buf][h * 128 + rd * 64 + wrow][0]);
    }
  };
  auto stB = [&](int buf, int kt, int h) {
    int kb = kt << 6;
#pragma unroll
    for (int rd = 0; rd < 2; rd++) {
      int R = h * 128 + rd * 64 + rr;
      gl2lds16(&Bg[(size_t)(nBase + R) * K + kb + ((sck ^ (R & 7)) << 3)],
               &Bs[buf][h * 128 + rd * 64 + wrow][0]);
    }
  };

  f32x4 acc[8][4];
  f32x4 zero = {0.f, 0.f, 0.f, 0.f};
#pragma unroll
  for (int i = 0; i < 8; i++)
#pragma unroll
    for (int j = 0; j < 4; j++) acc[i][j] = zero;

  const int nt = K >> 6;
  stA(0, 0, 0); stA(0, 0, 1); stB(0, 0, 0); stB(0, 0, 1);
  stA(1, 1, 0); stA(1, 1, 1); stB(1, 1, 0); stB(1, 1, 1);
  WAITVM(8);
  bar();

  bf16x8 af[4][2], bfr[4][2];
  for (int kt = 0; kt < nt; kt++) {
    const int buf = kt & 1;
    const bool pre = (kt + 2 < nt);
    // ---- phase 1: read A m0-3 + B n0-1; MFMA quadrant (0,0)
#pragma unroll
    for (int mi = 0; mi < 4; mi++) {
      int R = warp_m * 128 + mi * 16 + l15;
#pragma unroll
      for (int kh = 0; kh < 2; kh++)
        af[mi][kh] = *(const bf16x8*)&As[buf][R][((kh * 4 + quad) ^ (R & 7)) << 3];
    }
#pragma unroll
    for (int ni = 0; ni < 2; ni++) {
      int R = warp_n * 64 + ni * 16 + l15;
#pragma unroll
      for (int kh = 0; kh < 2; kh++)
        bfr[ni][kh] = *(const bf16x8*)&Bs[buf][R][((kh * 4 + quad) ^ (R & 7)) << 3];
    }
    bar();
    LGKM0;
    MFMA_QUAD(0, 0);
    bar();
    // ---- phase 2: read B n2-3; MFMA (0,1)
#pragma unroll
    for (int ni = 2; ni < 4; ni++) {
      int R = warp_n * 64 + ni * 16 + l15;
#pragma unroll
      for (int kh = 0; kh < 2; kh++)
        bfr[ni][kh] = *(const bf16x8*)&Bs[buf][R][((kh * 4 + quad) ^ (R & 7)) << 3];
    }
    bar();
    LGKM0;
    MFMA_QUAD(0, 1);
    bar();
    // ---- phase 3: read A m4-7; stage B of tile kt+2; MFMA (1,0)
#pragma unroll
    for (int mi = 0; mi < 4; mi++) {
      int R = warp_m * 128 + (4 + mi) * 16 + l15;
#pragma unroll
      for (int kh = 0; kh < 2; kh++)
        af[mi][kh] = *(const bf16x8*)&As[buf][R][((kh * 4 + quad) ^ (R & 7)) << 3];
    }
    if (pre) { stB(buf, kt + 2, 0); stB(buf, kt + 2, 1); }
    bar();
    LGKM0;
    MFMA_QUAD(1, 0);
    bar();
    // ---- phase 4: stage A of tile kt+2; MFMA (1,1); counted wait
    if (pre) { stA(buf, kt + 2, 0); stA(buf, kt + 2, 1); }
    bar();
    LGKM0;
    MFMA_QUAD(1, 1);
    if (pre) { WAITVM(8); } else { WAITVM(0); }
    bar();
  }

  // epilogue: gelu(acc + bias) -> bf16
  float bcol[4];
#pragma unroll
  for (int ni = 0; ni < 4; ni++) bcol[ni] = bias[nBase + warp_n * 64 + ni * 16 + l15];
#pragma unroll
  for (int mi = 0; mi < 8; mi++) {
#pragma unroll
    for (int r = 0; r < 4; r++) {
      int row = mBase + warp_m * 128 + mi * 16 + quad * 4 + r;
#pragma unroll
      for (int ni = 0; ni < 4; ni++) {
        int col = nBase + warp_n * 64 + ni * 16 + l15;
        float v = acc[mi][ni][r] + bcol[ni];
        v = 0.5f * v * (1.0f + erff(v * 0.70710678118654752f));
        outB[(size_t)row * N + col] = (__hip_bfloat16)v;
      }
    }
  }
}

// ------- MFMA GEMM: 2-phase template upgraded to prefetch-depth-2 (T4-lite) ----
// Triple-buffered LDS; stage(kt+2) issued at iteration top; end-of-iter is
// WAITVM(NLD) + raw s_barrier instead of __syncthreads' vmcnt(0) drain, so
// tile kt+1's loads get a full K-tile of compute as latency cover and tile
// kt+2's loads stay in flight ACROSS the barrier. WAR safe: the buffer
// stage(kt+2) overwrites was last ds_read in iter kt-1, and those reads
// completed before that iter's barrier (lgkm waits precede consuming MFMAs);
// per-wave WAITVM precedes bar() so cross-wave LDS data is visible.
template <int MODE, int TM>
__global__ __launch_bounds__(256) void gemm_bt(
    const __hip_bfloat16* __restrict__ A, const __hip_bfloat16* __restrict__ BT,
    int K, int N, const float* __restrict__ bias,
    const float* __restrict__ gate, const float* __restrict__ residF,
    const __hip_bfloat16* __restrict__ residB,
    float* __restrict__ outF, __hip_bfloat16* __restrict__ outB) {
  constexpr int MI = TM / 32;   // M-frags per wave
  constexpr int AR = TM / 32;   // A staging rounds (32 rows / round)
  __shared__ short As[3][TM][64];
  __shared__ short Bs[3][128][64];
  int t = threadIdx.x;
  int w = t >> 6, lane = t & 63, quad = lane >> 4, l15 = lane & 15;
  int wm = (w >> 1) * (TM / 2), wn = (w & 1) * 64;
  int mBase = blockIdx.y * TM, nBase = blockIdx.x * 128;
  f32x4 acc[MI][4];
  f32x4 zero = {0.f, 0.f, 0.f, 0.f};
#pragma unroll
  for (int i = 0; i < MI; i++)
#pragma unroll
    for (int j = 0; j < 4; j++) acc[i][j] = zero;
  const short* Ag = (const short*)A;
  const short* Bg = (const short*)BT;

  int rl = t >> 3;        // 0..31 row within round
  int sck = t & 7;        // storage 16B-chunk within row
  int wrow = w << 3;      // wave's first row within round

  auto stage = [&](int buf, int kt) {
    int kb = kt << 6;
#pragma unroll
    for (int rd = 0; rd < AR; rd++) {
      int R = (rd << 5) + rl;
      gl2lds16(&Ag[(size_t)(mBase + R) * K + kb + ((sck ^ (R & 7)) << 3)],
               &As[buf][(rd << 5) + wrow][0]);
    }
#pragma unroll
    for (int rd = 0; rd < 4; rd++) {
      int R = (rd << 5) + rl;
      gl2lds16(&Bg[(size_t)(nBase + R) * K + kb + ((sck ^ (R & 7)) << 3)],
               &Bs[buf][(rd << 5) + wrow][0]);
    }
  };

  const int nt = K >> 6;  // always >= 16 here
  stage(0, 0);
  stage(1, 1);
  // wait tile0 only (tile1's AR+4 loads stay outstanding)
  if constexpr (TM == 64) { WAITVM(6); } else { WAITVM(8); }
  bar();
  int cur = 0, nxt = 2;
  for (int kt = 0; kt < nt; kt++) {
    const bool pre = (kt + 2 < nt);
    if (pre) stage(nxt, kt + 2);
#pragma unroll
    for (int kh = 0; kh < 2; kh++) {
      bf16x8 af[MI], bfr[4];
      int dch = (kh << 2) + quad;
#pragma unroll
      for (int mi = 0; mi < MI; mi++) {
        int R = wm + mi * 16 + l15;
        af[mi] = *(const bf16x8*)&As[cur][R][(dch ^ (R & 7)) << 3];
      }
#pragma unroll
      for (int ni = 0; ni < 4; ni++) {
        int R = wn + ni * 16 + l15;
        bfr[ni] = *(const bf16x8*)&Bs[cur][R][(dch ^ (R & 7)) << 3];
      }
      __builtin_amdgcn_s_setprio(1);
#pragma unroll
      for (int mi = 0; mi < MI; mi++)
#pragma unroll
        for (int ni = 0; ni < 4; ni++)
          acc[mi][ni] = __builtin_amdgcn_mfma_f32_16x16x32_bf16(af[mi], bfr[ni], acc[mi][ni], 0, 0, 0);
      __builtin_amdgcn_s_setprio(0);
    }
    // tile kt+1 must be landed before next iter reads it; kt+2 stays in flight
    if (pre) {
      if constexpr (TM == 64) { WAITVM(6); } else { WAITVM(8); }
    } else {
      WAITVM(0);
    }
    bar();
    cur = (cur == 2) ? 0 : cur + 1;
    nxt = (nxt == 2) ? 0 : nxt + 1;
  }

#pragma unroll
  for (int mi = 0; mi < MI; mi++) {
#pragma unroll
    for (int r = 0; r < 4; r++) {
      int row = mBase + wm + mi * 16 + quad * 4 + r;
#pragma unroll
      for (int ni = 0; ni < 4; ni++) {
        int col = nBase + wn + ni * 16 + l15;
        float v = acc[mi][ni][r];
        if (MODE == 0) {
          float g = gate[(row >> 11) * EMB + col];
          v = g * (v + bias[col]) + residF[(size_t)row * N + col];
          outF[(size_t)row * N + col] = v;
        } else if (MODE == 1) {
          v += bias[col];
          v = 0.5f * v * (1.0f + erff(v * 0.70710678118654752f));  // exact gelu
          outB[(size_t)row * N + col] = (__hip_bfloat16)v;
        } else {
          v += bias[col] + (float)residB[(size_t)row * N + col];
          outF[(size_t)row * N + col] = v;
        }
      }
    }
  }
}

// ---------------- LayerNorm (fp32 in; bf16 or fp32 out) ----------------
__device__ __forceinline__ float block_sum_256(float v) {
  __shared__ float sb[4];
#pragma unroll
  for (int off = 32; off > 0; off >>= 1) v += __shfl_down(v, off);
  int w = threadIdx.x >> 6, ln = threadIdx.x & 63;
  if (ln == 0) sb[w] = v;
  __syncthreads();
  float r = sb[0] + sb[1] + sb[2] + sb[3];
  __syncthreads();
  return r;
}

template <bool TO_BF16>
__global__ __launch_bounds__(256) void ln_kernel(
    const float* __restrict__ y, const float* __restrict__ g,
    const float* __restrict__ b, __hip_bfloat16* __restrict__ outB,
    float* __restrict__ outF) {
  size_t row = blockIdx.x;
  const float* yr = y + row * EMB;
  float v[4];
#pragma unroll
  for (int i = 0; i < 4; i++) v[i] = yr[threadIdx.x + i * 256];
  float s = block_sum_256(v[0] + v[1] + v[2] + v[3]);
  float mu = s * (1.f / (float)EMB);
  float q = 0.f;
#pragma unroll
  for (int i = 0; i < 4; i++) { float d = v[i] - mu; q += d * d; }
  q = block_sum_256(q);
  float rs = rsqrtf(q * (1.f / (float)EMB) + 1e-5f);
#pragma unroll
  for (int i = 0; i < 4; i++) {
    int e = threadIdx.x + i * 256;
    float o = (v[i] - mu) * rs * g[e] + b[e];
    if (TO_BF16) outB[row * EMB + e] = (__hip_bfloat16)o;
    else         outF[row * EMB + e] = o;
  }
}

extern "C" void kernel_launch(void* const* d_in, const int* in_sizes, int n_in,
                              void* d_out, int out_size, void* d_ws, size_t ws_size,
                              hipStream_t stream) {
  const float* Val = (const float*)d_in[0];
  const float* Key = (const float*)d_in[1];
  const float* Qry = (const float*)d_in[2];
  const float* Wo  = (const float*)d_in[4];
  const float* bo  = (const float*)d_in[5];
  const float* Wg  = (const float*)d_in[6];
  const float* bg  = (const float*)d_in[7];
  const float* g1  = (const float*)d_in[8];
  const float* b1  = (const float*)d_in[9];
  const float* g2  = (const float*)d_in[10];
  const float* b2  = (const float*)d_in[11];
  const float* W1  = (const float*)d_in[12];
  const float* bf1 = (const float*)d_in[13];
  const float* W2  = (const float*)d_in[14];
  const float* bf2 = (const float*)d_in[15];
  float* out = (float*)d_out;

  char* ws = (char*)d_ws;
  size_t off = 0;
  auto alloc = [&](size_t bytes) {
    char* p = ws + off;
    off += (bytes + 255) & ~(size_t)255;
    return p;
  };
  const size_t MB = 1024 * 1024;
  bool bigws = ws_size >= 78 * MB;  // ws_size constant across calls

  __hip_bfloat16* WoT = (__hip_bfloat16*)alloc((size_t)EMB * EMB * 2);           // 2 MB
  __hip_bfloat16* W1T = (__hip_bfloat16*)alloc((size_t)EMB * FF_DIM * 2);        // 8 MB
  __hip_bfloat16* W2T = (__hip_bfloat16*)alloc((size_t)EMB * FF_DIM * 2);        // 8 MB
  size_t kvRegion = bigws ? (size_t)BATCH * S_LEN * FF_DIM * 2
                          : (size_t)S_LEN * FF_DIM * 2;
  char* kvBase = alloc(kvRegion);
  __hip_bfloat16* Kpk  = (__hip_bfloat16*)kvBase;                                // 8 MB
  __hip_bfloat16* Vtb  = (__hip_bfloat16*)(kvBase + 8 * MB);                     // 8 MB
  __hip_bfloat16* Hbuf = (__hip_bfloat16*)kvBase;
  __hip_bfloat16* attnO = (__hip_bfloat16*)alloc((size_t)BATCH * S_LEN * EMB * 2);// 8 MB
  float* ybuf = (float*)alloc((size_t)BATCH * S_LEN * EMB * 4);                  // 16 MB
  float* xavg = (float*)alloc(BATCH * EMB * 4);
  float* gate = (float*)alloc(BATCH * EMB * 4);
  __hip_bfloat16* xb = attnO;
  float* zbuf = ybuf;

  transpose_all<<<2304, 256, 0, stream>>>(Wo, W1, W2, WoT, W1T, W2T);
  zero_f32<<<BATCH * EMB / 256, 256, 0, stream>>>(xavg);
  xavg_partial<<<dim3(128, BATCH), 256, 0, stream>>>(Qry, xavg);
  gate_kernel<<<dim3(16, BATCH), 256, 0, stream>>>(xavg, Wg, bg, gate);
  pack_kv<<<dim3(32, NH, BATCH), 256, 0, stream>>>(Key, Val, Kpk, Vtb);
  flash_attn_mfma<<<1024, 256, 0, stream>>>(Qry, Kpk, Vtb, attnO);
  gemm_bt<0, 64><<<dim3(8, 64), 256, 0, stream>>>(attnO, WoT, EMB, EMB, bo, gate, Qry, nullptr, ybuf, nullptr);
  ln_kernel<true><<<4096, 256, 0, stream>>>(ybuf, g1, b1, xb, nullptr);
  if (bigws) {
    gemm8p_gelu<<<256, 512, 0, stream>>>(xb, W1T, EMB, FF_DIM, bf1, Hbuf);
    gemm_bt<2, 64><<<dim3(8, 64), 256, 0, stream>>>(Hbuf, W2T, FF_DIM, EMB, bf2, nullptr, nullptr, xb, zbuf, nullptr);
  } else {
    for (int b = 0; b < BATCH; b++) {
      const __hip_bfloat16* xbb = xb + (size_t)b * S_LEN * EMB;
      gemm_bt<1, 128><<<dim3(32, 16), 256, 0, stream>>>(xbb, W1T, EMB, FF_DIM, bf1, nullptr, nullptr, nullptr, nullptr, Hbuf);
      gemm_bt<2, 64><<<dim3(8, 32), 256, 0, stream>>>(Hbuf, W2T, FF_DIM, EMB, bf2, nullptr, nullptr, xbb,
                                                      zbuf + (size_t)b * S_LEN * EMB, nullptr);
    }
  }
  ln_kernel<false><<<4096, 256, 0, stream>>>(zbuf, g2, b2, nullptr, out);
}

// Round 6
// 431.263 us; speedup vs baseline: 1.0207x; 1.0207x over previous
//
#include <hip/hip_runtime.h>
#include <hip/hip_bf16.h>

#define S_LEN 2048
#define EMB   1024
#define NH    16
#define HD    64
#define FF_DIM 4096
#define BATCH 2

typedef __attribute__((ext_vector_type(8))) short bf16x8;
typedef __attribute__((ext_vector_type(4))) float f32x4;

__device__ __forceinline__ short f2bf(float x) {
  __hip_bfloat16 h = (__hip_bfloat16)x;
  return *(short*)&h;
}
__device__ __forceinline__ bf16x8 pack8(float4 a, float4 b) {
  bf16x8 o;
  o[0] = f2bf(a.x); o[1] = f2bf(a.y); o[2] = f2bf(a.z); o[3] = f2bf(a.w);
  o[4] = f2bf(b.x); o[5] = f2bf(b.y); o[6] = f2bf(b.z); o[7] = f2bf(b.w);
  return o;
}

// async global->LDS, 16B/lane; LDS dest = wave-uniform base + lane*16
__device__ __forceinline__ void gl2lds16(const void* g, void* l) {
  __builtin_amdgcn_global_load_lds(
      (const __attribute__((address_space(1))) unsigned*)g,
      (__attribute__((address_space(3))) unsigned*)l, 16, 0, 0);
}

// raw barrier WITHOUT the vmcnt(0) drain __syncthreads would emit.
__device__ __forceinline__ void bar() {
  asm volatile("" ::: "memory");
  __builtin_amdgcn_s_barrier();
  asm volatile("" ::: "memory");
}
#define WAITVM(n) asm volatile("s_waitcnt vmcnt(" #n ")" ::: "memory")

// ------------- fused fp32->bf16 convert+transpose for Wo, W1, W2 -------------
__device__ __forceinline__ void transpose_tile(
    const float* in, short* outS, int R, int C, int bx, int by, int t) {
  __shared__ short Ts[64][65];
  int cb = bx * 64, rb = by * 64;
  for (int idx = t; idx < 4096; idx += 256) {
    int r = idx >> 6, c = idx & 63;
    Ts[r][c] = f2bf(in[(size_t)(rb + r) * C + cb + c]);
  }
  __syncthreads();
  for (int idx = t; idx < 4096; idx += 256) {
    int oc = idx >> 6, orr = idx & 63;
    outS[(size_t)(cb + oc) * R + rb + orr] = Ts[orr][oc];
  }
}

__global__ __launch_bounds__(256) void transpose_all(
    const float* __restrict__ Wo, const float* __restrict__ W1,
    const float* __restrict__ W2, __hip_bfloat16* __restrict__ WoT,
    __hip_bfloat16* __restrict__ W1T, __hip_bfloat16* __restrict__ W2T) {
  int id = blockIdx.x, t = threadIdx.x;
  if (id < 256)        transpose_tile(Wo, (short*)WoT, EMB, EMB,    id & 15,          id >> 4,          t);
  else if (id < 1280)  transpose_tile(W1, (short*)W1T, EMB, FF_DIM, (id - 256) & 63,  (id - 256) >> 6,  t);
  else                 transpose_tile(W2, (short*)W2T, FF_DIM, EMB, (id - 1280) & 15, (id - 1280) >> 4, t);
}

// ---------------- xavg: zero + atomic partial sums (coalesced) ----------------
__global__ __launch_bounds__(256) void zero_f32(float* __restrict__ p) {
  p[blockIdx.x * 256 + threadIdx.x] = 0.f;
}

__global__ __launch_bounds__(256) void xavg_partial(
    const float* __restrict__ Q, float* __restrict__ xavg) {
  int b = blockIdx.y;
  int s0 = blockIdx.x * 16;
  int t = threadIdx.x;
  const float* base = Q + ((size_t)b * S_LEN + s0) * EMB + 4 * t;
  float4 acc = {0.f, 0.f, 0.f, 0.f};
#pragma unroll 4
  for (int r = 0; r < 16; r++) {
    float4 v = *(const float4*)(base + (size_t)r * EMB);
    acc.x += v.x; acc.y += v.y; acc.z += v.z; acc.w += v.w;
  }
  float* dst = xavg + b * EMB + 4 * t;
  const float inv = 1.f / (float)S_LEN;
  atomicAdd(dst + 0, acc.x * inv);
  atomicAdd(dst + 1, acc.y * inv);
  atomicAdd(dst + 2, acc.z * inv);
  atomicAdd(dst + 3, acc.w * inv);
}

// ---------------- gate = sigmoid(xavg @ Wg + bg) ----------------
__global__ __launch_bounds__(256) void gate_kernel(
    const float* __restrict__ xavg, const float* __restrict__ Wg,
    const float* __restrict__ bg, float* __restrict__ gate) {
  __shared__ float red[4][64];
  int b = blockIdx.y;
  int nl = threadIdx.x & 63;
  int n = blockIdx.x * 64 + nl;
  int kg = threadIdx.x >> 6;
  const float* xa = xavg + b * EMB;
  float s = 0.f;
#pragma unroll 4
  for (int k = kg * 256; k < kg * 256 + 256; k++)
    s += xa[k] * Wg[(size_t)k * EMB + n];
  red[kg][nl] = s;
  __syncthreads();
  if (kg == 0) {
    float tot = red[0][nl] + red[1][nl] + red[2][nl] + red[3][nl] + bg[n];
    gate[b * EMB + n] = 1.f / (1.f + __expf(-tot));
  }
}

// ---------------- pack K/V: fp32 [b,s,h*64] -> bf16 Kp[b,h,s,d], Vt[b,h,d,s] ----
__global__ __launch_bounds__(256) void pack_kv(
    const float* __restrict__ Kg, const float* __restrict__ Vg,
    __hip_bfloat16* __restrict__ Kp, __hip_bfloat16* __restrict__ Vt) {
  __shared__ short Vs[64][72];
  int s0 = blockIdx.x * 64, h = blockIdx.y, b = blockIdx.z;
  int t = threadIdx.x, r = t >> 2, c = (t & 3) * 16;
  size_t gin = ((size_t)b * S_LEN + s0 + r) * EMB + h * HD + c;
  {
    float4 a0 = *(const float4*)(Kg + gin);
    float4 a1 = *(const float4*)(Kg + gin + 4);
    float4 a2 = *(const float4*)(Kg + gin + 8);
    float4 a3 = *(const float4*)(Kg + gin + 12);
    short* kp = (short*)Kp + (((size_t)b * NH + h) * S_LEN + s0 + r) * HD + c;
    *(bf16x8*)(kp)     = pack8(a0, a1);
    *(bf16x8*)(kp + 8) = pack8(a2, a3);
  }
  {
    float4 a0 = *(const float4*)(Vg + gin);
    float4 a1 = *(const float4*)(Vg + gin + 4);
    float4 a2 = *(const float4*)(Vg + gin + 8);
    float4 a3 = *(const float4*)(Vg + gin + 12);
    *(bf16x8*)&Vs[r][c]     = pack8(a0, a1);
    *(bf16x8*)&Vs[r][c + 8] = pack8(a2, a3);
  }
  __syncthreads();
  bf16x8 o0, o1;
#pragma unroll
  for (int j = 0; j < 8; j++) o0[j] = Vs[c + j][r];
#pragma unroll
  for (int j = 0; j < 8; j++) o1[j] = Vs[c + 8 + j][r];
  short* vp = (short*)Vt + (((size_t)b * NH + h) * HD + r) * S_LEN + s0 + c;
  *(bf16x8*)(vp)     = o0;
  *(bf16x8*)(vp + 8) = o1;
}

// ---------------- causal flash attention, MFMA bf16 ----------------
__global__ __launch_bounds__(256) void flash_attn_mfma(
    const float* __restrict__ Q, const __hip_bfloat16* __restrict__ Kp,
    const __hip_bfloat16* __restrict__ Vtb, __hip_bfloat16* __restrict__ O) {
  __shared__ short Ks[64][72];
  __shared__ short Vt[64][72];
  __shared__ short Ps[4][16][72];  // bf16 P, per wave; row stride 144B (16B-mult)
  int t = threadIdx.x;
  int w = t >> 6, lane = t & 63, quad = lane >> 4, l15 = lane & 15;
  int j = blockIdx.x;
  int p = j & 255, g = j >> 8;
  int bh = p & 31, c_ = p >> 5;
  int qb = (g == 0) ? c_ : (g == 1) ? (15 - c_) : (g == 2) ? (16 + c_) : (31 - c_);
  int h = bh & 15, b = bh >> 4;
  size_t base = ((size_t)b * S_LEN) * EMB + h * HD;
  const short* kpb = (const short*)Kp + ((size_t)b * NH + h) * S_LEN * HD;
  const short* vtb = (const short*)Vtb + ((size_t)b * NH + h) * HD * S_LEN;

  // Q A-fragments, pre-scaled by 1/sqrt(HD)=0.125
  bf16x8 qf[2];
  {
    const float* qrow = Q + base + (size_t)(qb * 64 + w * 16 + l15) * EMB;
#pragma unroll
    for (int kc = 0; kc < 2; kc++) {
      float4 a = *(const float4*)(qrow + kc * 32 + quad * 8);
      float4 c = *(const float4*)(qrow + kc * 32 + quad * 8 + 4);
      a.x *= 0.125f; a.y *= 0.125f; a.z *= 0.125f; a.w *= 0.125f;
      c.x *= 0.125f; c.y *= 0.125f; c.z *= 0.125f; c.w *= 0.125f;
      qf[kc] = pack8(a, c);
    }
  }

  f32x4 acc[4];
  float lsum[4];
  f32x4 zero = {0.f, 0.f, 0.f, 0.f};
#pragma unroll
  for (int n = 0; n < 4; n++) acc[n] = zero;
#pragma unroll
  for (int r = 0; r < 4; r++) lsum[r] = 0.f;

  int r0 = t >> 2, c0 = (t & 3) * 16;
  bf16x8 kf0, kf1, vf0, vf1;  // prefetch regs
  {
    const short* kr = kpb + (size_t)r0 * HD + c0;
    kf0 = *(const bf16x8*)(kr); kf1 = *(const bf16x8*)(kr + 8);
    const short* vr = vtb + (size_t)r0 * S_LEN + c0;
    vf0 = *(const bf16x8*)(vr); vf1 = *(const bf16x8*)(vr + 8);
  }

  for (int kt = 0; kt <= qb; kt++) {
    __syncthreads();
    *(bf16x8*)&Ks[r0][c0]     = kf0;
    *(bf16x8*)&Ks[r0][c0 + 8] = kf1;
    *(bf16x8*)&Vt[r0][c0]     = vf0;
    *(bf16x8*)&Vt[r0][c0 + 8] = vf1;
    __syncthreads();
    if (kt < qb) {  // prefetch next tile during compute
      const short* kr = kpb + (size_t)((kt + 1) * 64 + r0) * HD + c0;
      kf0 = *(const bf16x8*)(kr); kf1 = *(const bf16x8*)(kr + 8);
      const short* vr = vtb + (size_t)r0 * S_LEN + (kt + 1) * 64 + c0;
      vf0 = *(const bf16x8*)(vr); vf1 = *(const bf16x8*)(vr + 8);
    }

    // S = (Q/8) K^T   (T5: boost wave priority through the MFMA cluster)
    f32x4 sc[4];
#pragma unroll
    for (int n = 0; n < 4; n++) sc[n] = zero;
    __builtin_amdgcn_s_setprio(1);
#pragma unroll
    for (int n = 0; n < 4; n++)
#pragma unroll
      for (int kc = 0; kc < 2; kc++) {
        bf16x8 kf = *(const bf16x8*)&Ks[n * 16 + l15][kc * 32 + quad * 8];
        sc[n] = __builtin_amdgcn_mfma_f32_16x16x32_bf16(qf[kc], kf, sc[n], 0, 0, 0);
      }
    __builtin_amdgcn_s_setprio(0);

    bool diag = (kt == qb);
#pragma unroll
    for (int r = 0; r < 4; r++) {
      float p0 = __expf(sc[0][r]);
      float p1 = __expf(sc[1][r]);
      float p2 = __expf(sc[2][r]);
      float p3 = __expf(sc[3][r]);
      if (diag) {
        int rowL = w * 16 + quad * 4 + r;
        if (l15      > rowL) p0 = 0.f;
        if (l15 + 16 > rowL) p1 = 0.f;
        if (l15 + 32 > rowL) p2 = 0.f;
        if (l15 + 48 > rowL) p3 = 0.f;
      }
      lsum[r] += (p0 + p1) + (p2 + p3);
      short* prow = &Ps[w][quad * 4 + r][l15];
      prow[0]  = f2bf(p0);
      prow[16] = f2bf(p1);
      prow[32] = f2bf(p2);
      prow[48] = f2bf(p3);
    }
    // drain same-wave DS writes before cross-lane reads (per-wave P region)
    asm volatile("s_waitcnt lgkmcnt(0)" ::: "memory");

    bf16x8 pf0 = *(const bf16x8*)&Ps[w][l15][quad * 8];
    bf16x8 pf1 = *(const bf16x8*)&Ps[w][l15][32 + quad * 8];
    __builtin_amdgcn_s_setprio(1);
#pragma unroll
    for (int n = 0; n < 4; n++) {
      bf16x8 vfa = *(const bf16x8*)&Vt[n * 16 + l15][quad * 8];
      acc[n] = __builtin_amdgcn_mfma_f32_16x16x32_bf16(pf0, vfa, acc[n], 0, 0, 0);
      bf16x8 vfb = *(const bf16x8*)&Vt[n * 16 + l15][32 + quad * 8];
      acc[n] = __builtin_amdgcn_mfma_f32_16x16x32_bf16(pf1, vfb, acc[n], 0, 0, 0);
    }
    __builtin_amdgcn_s_setprio(0);
  }

  // deferred row-sum: one shuffle reduction across the 16-lane row group
#pragma unroll
  for (int r = 0; r < 4; r++) {
    float l = lsum[r];
#pragma unroll
    for (int off = 1; off < 16; off <<= 1) l += __shfl_xor(l, off);
    float invl = 1.f / l;
    size_t orow = base + (size_t)(qb * 64 + w * 16 + quad * 4 + r) * EMB;
#pragma unroll
    for (int n = 0; n < 4; n++)
      O[orow + n * 16 + l15] = (__hip_bfloat16)(acc[n][r] * invl);
  }
}

// ------- MFMA GEMM: 2-phase template with prefetch-depth-2 (T4-lite) ----------
// Triple-buffered LDS; stage(kt+2) issued at iteration top; end-of-iter is
// WAITVM(NLD) + raw s_barrier instead of __syncthreads' vmcnt(0) drain, so
// tile kt+1's loads get a full K-tile of compute as latency cover and tile
// kt+2's loads stay in flight ACROSS the barrier. (Harness-verified round 5:
// passed, and Δ≈−32 µs on mode0+FFN2.) WAR safe: the buffer stage(kt+2)
// overwrites was last ds_read in iter kt-1; those reads completed before that
// iter's barrier; per-wave WAITVM precedes bar() for cross-wave visibility.
template <int MODE, int TM>
__global__ __launch_bounds__(256) void gemm_bt(
    const __hip_bfloat16* __restrict__ A, const __hip_bfloat16* __restrict__ BT,
    int K, int N, const float* __restrict__ bias,
    const float* __restrict__ gate, const float* __restrict__ residF,
    const __hip_bfloat16* __restrict__ residB,
    float* __restrict__ outF, __hip_bfloat16* __restrict__ outB) {
  constexpr int MI = TM / 32;   // M-frags per wave
  constexpr int AR = TM / 32;   // A staging rounds (32 rows / round)
  __shared__ short As[3][TM][64];
  __shared__ short Bs[3][128][64];
  int t = threadIdx.x;
  int w = t >> 6, lane = t & 63, quad = lane >> 4, l15 = lane & 15;
  int wm = (w >> 1) * (TM / 2), wn = (w & 1) * 64;
  int mBase = blockIdx.y * TM, nBase = blockIdx.x * 128;
  f32x4 acc[MI][4];
  f32x4 zero = {0.f, 0.f, 0.f, 0.f};
#pragma unroll
  for (int i = 0; i < MI; i++)
#pragma unroll
    for (int j = 0; j < 4; j++) acc[i][j] = zero;
  const short* Ag = (const short*)A;
  const short* Bg = (const short*)BT;

  int rl = t >> 3;        // 0..31 row within round
  int sck = t & 7;        // storage 16B-chunk within row
  int wrow = w << 3;      // wave's first row within round

  auto stage = [&](int buf, int kt) {
    int kb = kt << 6;
#pragma unroll
    for (int rd = 0; rd < AR; rd++) {
      int R = (rd << 5) + rl;
      gl2lds16(&Ag[(size_t)(mBase + R) * K + kb + ((sck ^ (R & 7)) << 3)],
               &As[buf][(rd << 5) + wrow][0]);
    }
#pragma unroll
    for (int rd = 0; rd < 4; rd++) {
      int R = (rd << 5) + rl;
      gl2lds16(&Bg[(size_t)(nBase + R) * K + kb + ((sck ^ (R & 7)) << 3)],
               &Bs[buf][(rd << 5) + wrow][0]);
    }
  };

  const int nt = K >> 6;  // always >= 16 here
  stage(0, 0);
  stage(1, 1);
  // wait tile0 only (tile1's AR+4 loads stay outstanding)
  if constexpr (TM == 64) { WAITVM(6); } else { WAITVM(8); }
  bar();
  int cur = 0, nxt = 2;
  for (int kt = 0; kt < nt; kt++) {
    const bool pre = (kt + 2 < nt);
    if (pre) stage(nxt, kt + 2);
#pragma unroll
    for (int kh = 0; kh < 2; kh++) {
      bf16x8 af[MI], bfr[4];
      int dch = (kh << 2) + quad;
#pragma unroll
      for (int mi = 0; mi < MI; mi++) {
        int R = wm + mi * 16 + l15;
        af[mi] = *(const bf16x8*)&As[cur][R][(dch ^ (R & 7)) << 3];
      }
#pragma unroll
      for (int ni = 0; ni < 4; ni++) {
        int R = wn + ni * 16 + l15;
        bfr[ni] = *(const bf16x8*)&Bs[cur][R][(dch ^ (R & 7)) << 3];
      }
      __builtin_amdgcn_s_setprio(1);
#pragma unroll
      for (int mi = 0; mi < MI; mi++)
#pragma unroll
        for (int ni = 0; ni < 4; ni++)
          acc[mi][ni] = __builtin_amdgcn_mfma_f32_16x16x32_bf16(af[mi], bfr[ni], acc[mi][ni], 0, 0, 0);
      __builtin_amdgcn_s_setprio(0);
    }
    // tile kt+1 must be landed before next iter reads it; kt+2 stays in flight
    if (pre) {
      if constexpr (TM == 64) { WAITVM(6); } else { WAITVM(8); }
    } else {
      WAITVM(0);
    }
    bar();
    cur = (cur == 2) ? 0 : cur + 1;
    nxt = (nxt == 2) ? 0 : nxt + 1;
  }

#pragma unroll
  for (int mi = 0; mi < MI; mi++) {
#pragma unroll
    for (int r = 0; r < 4; r++) {
      int row = mBase + wm + mi * 16 + quad * 4 + r;
#pragma unroll
      for (int ni = 0; ni < 4; ni++) {
        int col = nBase + wn + ni * 16 + l15;
        float v = acc[mi][ni][r];
        if (MODE == 0) {
          float g = gate[(row >> 11) * EMB + col];
          v = g * (v + bias[col]) + residF[(size_t)row * N + col];
          outF[(size_t)row * N + col] = v;
        } else if (MODE == 1) {
          v += bias[col];
          v = 0.5f * v * (1.0f + erff(v * 0.70710678118654752f));  // exact gelu
          outB[(size_t)row * N + col] = (__hip_bfloat16)v;
        } else {
          v += bias[col] + (float)residB[(size_t)row * N + col];
          outF[(size_t)row * N + col] = v;
        }
      }
    }
  }
}

// ---------------- LayerNorm (fp32 in; bf16 or fp32 out) ----------------
__device__ __forceinline__ float block_sum_256(float v) {
  __shared__ float sb[4];
#pragma unroll
  for (int off = 32; off > 0; off >>= 1) v += __shfl_down(v, off);
  int w = threadIdx.x >> 6, ln = threadIdx.x & 63;
  if (ln == 0) sb[w] = v;
  __syncthreads();
  float r = sb[0] + sb[1] + sb[2] + sb[3];
  __syncthreads();
  return r;
}

template <bool TO_BF16>
__global__ __launch_bounds__(256) void ln_kernel(
    const float* __restrict__ y, const float* __restrict__ g,
    const float* __restrict__ b, __hip_bfloat16* __restrict__ outB,
    float* __restrict__ outF) {
  size_t row = blockIdx.x;
  const float* yr = y + row * EMB;
  float v[4];
#pragma unroll
  for (int i = 0; i < 4; i++) v[i] = yr[threadIdx.x + i * 256];
  float s = block_sum_256(v[0] + v[1] + v[2] + v[3]);
  float mu = s * (1.f / (float)EMB);
  float q = 0.f;
#pragma unroll
  for (int i = 0; i < 4; i++) { float d = v[i] - mu; q += d * d; }
  q = block_sum_256(q);
  float rs = rsqrtf(q * (1.f / (float)EMB) + 1e-5f);
#pragma unroll
  for (int i = 0; i < 4; i++) {
    int e = threadIdx.x + i * 256;
    float o = (v[i] - mu) * rs * g[e] + b[e];
    if (TO_BF16) outB[row * EMB + e] = (__hip_bfloat16)o;
    else         outF[row * EMB + e] = o;
  }
}

extern "C" void kernel_launch(void* const* d_in, const int* in_sizes, int n_in,
                              void* d_out, int out_size, void* d_ws, size_t ws_size,
                              hipStream_t stream) {
  const float* Val = (const float*)d_in[0];
  const float* Key = (const float*)d_in[1];
  const float* Qry = (const float*)d_in[2];
  const float* Wo  = (const float*)d_in[4];
  const float* bo  = (const float*)d_in[5];
  const float* Wg  = (const float*)d_in[6];
  const float* bg  = (const float*)d_in[7];
  const float* g1  = (const float*)d_in[8];
  const float* b1  = (const float*)d_in[9];
  const float* g2  = (const float*)d_in[10];
  const float* b2  = (const float*)d_in[11];
  const float* W1  = (const float*)d_in[12];
  const float* bf1 = (const float*)d_in[13];
  const float* W2  = (const float*)d_in[14];
  const float* bf2 = (const float*)d_in[15];
  float* out = (float*)d_out;

  char* ws = (char*)d_ws;
  size_t off = 0;
  auto alloc = [&](size_t bytes) {
    char* p = ws + off;
    off += (bytes + 255) & ~(size_t)255;
    return p;
  };
  const size_t MB = 1024 * 1024;
  bool bigws = ws_size >= 78 * MB;  // ws_size constant across calls

  __hip_bfloat16* WoT = (__hip_bfloat16*)alloc((size_t)EMB * EMB * 2);           // 2 MB
  __hip_bfloat16* W1T = (__hip_bfloat16*)alloc((size_t)EMB * FF_DIM * 2);        // 8 MB
  __hip_bfloat16* W2T = (__hip_bfloat16*)alloc((size_t)EMB * FF_DIM * 2);        // 8 MB
  size_t kvRegion = bigws ? (size_t)BATCH * S_LEN * FF_DIM * 2
                          : (size_t)S_LEN * FF_DIM * 2;
  char* kvBase = alloc(kvRegion);
  __hip_bfloat16* Kpk  = (__hip_bfloat16*)kvBase;                                // 8 MB
  __hip_bfloat16* Vtb  = (__hip_bfloat16*)(kvBase + 8 * MB);                     // 8 MB
  __hip_bfloat16* Hbuf = (__hip_bfloat16*)kvBase;
  __hip_bfloat16* attnO = (__hip_bfloat16*)alloc((size_t)BATCH * S_LEN * EMB * 2);// 8 MB
  float* ybuf = (float*)alloc((size_t)BATCH * S_LEN * EMB * 4);                  // 16 MB
  float* xavg = (float*)alloc(BATCH * EMB * 4);
  float* gate = (float*)alloc(BATCH * EMB * 4);
  __hip_bfloat16* xb = attnO;
  float* zbuf = ybuf;

  transpose_all<<<2304, 256, 0, stream>>>(Wo, W1, W2, WoT, W1T, W2T);
  zero_f32<<<BATCH * EMB / 256, 256, 0, stream>>>(xavg);
  xavg_partial<<<dim3(128, BATCH), 256, 0, stream>>>(Qry, xavg);
  gate_kernel<<<dim3(16, BATCH), 256, 0, stream>>>(xavg, Wg, bg, gate);
  pack_kv<<<dim3(32, NH, BATCH), 256, 0, stream>>>(Key, Val, Kpk, Vtb);
  flash_attn_mfma<<<1024, 256, 0, stream>>>(Qry, Kpk, Vtb, attnO);
  gemm_bt<0, 64><<<dim3(8, 64), 256, 0, stream>>>(attnO, WoT, EMB, EMB, bo, gate, Qry, nullptr, ybuf, nullptr);
  ln_kernel<true><<<4096, 256, 0, stream>>>(ybuf, g1, b1, xb, nullptr);
  if (bigws) {
    gemm_bt<1, 64><<<dim3(32, 64), 256, 0, stream>>>(xb, W1T, EMB, FF_DIM, bf1, nullptr, nullptr, nullptr, nullptr, Hbuf);
    gemm_bt<2, 64><<<dim3(8, 64), 256, 0, stream>>>(Hbuf, W2T, FF_DIM, EMB, bf2, nullptr, nullptr, xb, zbuf, nullptr);
  } else {
    for (int b = 0; b < BATCH; b++) {
      const __hip_bfloat16* xbb = xb + (size_t)b * S_LEN * EMB;
      gemm_bt<1, 64><<<dim3(32, 32), 256, 0, stream>>>(xbb, W1T, EMB, FF_DIM, bf1, nullptr, nullptr, nullptr, nullptr, Hbuf);
      gemm_bt<2, 64><<<dim3(8, 32), 256, 0, stream>>>(Hbuf, W2T, FF_DIM, EMB, bf2, nullptr, nullptr, xbb,
                                                      zbuf + (size_t)b * S_LEN * EMB, nullptr);
    }
  }
  ln_kernel<false><<<4096, 256, 0, stream>>>(zbuf, g2, b2, nullptr, out);
}

// Round 7
// 409.906 us; speedup vs baseline: 1.0738x; 1.0521x over previous
//
#include <hip/hip_runtime.h>
#include <hip/hip_bf16.h>

#define S_LEN 2048
#define EMB   1024
#define NH    16
#define HD    64
#define FF_DIM 4096
#define BATCH 2

typedef __attribute__((ext_vector_type(8))) short bf16x8;
typedef __attribute__((ext_vector_type(4))) float f32x4;

__device__ __forceinline__ short f2bf(float x) {
  __hip_bfloat16 h = (__hip_bfloat16)x;
  return *(short*)&h;
}
__device__ __forceinline__ bf16x8 pack8(float4 a, float4 b) {
  bf16x8 o;
  o[0] = f2bf(a.x); o[1] = f2bf(a.y); o[2] = f2bf(a.z); o[3] = f2bf(a.w);
  o[4] = f2bf(b.x); o[5] = f2bf(b.y); o[6] = f2bf(b.z); o[7] = f2bf(b.w);
  return o;
}

// async global->LDS, 16B/lane; LDS dest = wave-uniform base + lane*16
__device__ __forceinline__ void gl2lds16(const void* g, void* l) {
  __builtin_amdgcn_global_load_lds(
      (const __attribute__((address_space(1))) unsigned*)g,
      (__attribute__((address_space(3))) unsigned*)l, 16, 0, 0);
}

// ------------- fused fp32->bf16 convert+transpose for Wo, W1, W2 -------------
__device__ __forceinline__ void transpose_tile(
    const float* in, short* outS, int R, int C, int bx, int by, int t) {
  __shared__ short Ts[64][65];
  int cb = bx * 64, rb = by * 64;
  for (int idx = t; idx < 4096; idx += 256) {
    int r = idx >> 6, c = idx & 63;
    Ts[r][c] = f2bf(in[(size_t)(rb + r) * C + cb + c]);
  }
  __syncthreads();
  for (int idx = t; idx < 4096; idx += 256) {
    int oc = idx >> 6, orr = idx & 63;
    outS[(size_t)(cb + oc) * R + rb + orr] = Ts[orr][oc];
  }
}

__global__ __launch_bounds__(256) void transpose_all(
    const float* __restrict__ Wo, const float* __restrict__ W1,
    const float* __restrict__ W2, __hip_bfloat16* __restrict__ WoT,
    __hip_bfloat16* __restrict__ W1T, __hip_bfloat16* __restrict__ W2T) {
  int id = blockIdx.x, t = threadIdx.x;
  if (id < 256)        transpose_tile(Wo, (short*)WoT, EMB, EMB,    id & 15,          id >> 4,          t);
  else if (id < 1280)  transpose_tile(W1, (short*)W1T, EMB, FF_DIM, (id - 256) & 63,  (id - 256) >> 6,  t);
  else                 transpose_tile(W2, (short*)W2T, FF_DIM, EMB, (id - 1280) & 15, (id - 1280) >> 4, t);
}

// ---------------- xavg: zero + atomic partial sums (coalesced) ----------------
__global__ __launch_bounds__(256) void zero_f32(float* __restrict__ p) {
  p[blockIdx.x * 256 + threadIdx.x] = 0.f;
}

__global__ __launch_bounds__(256) void xavg_partial(
    const float* __restrict__ Q, float* __restrict__ xavg) {
  int b = blockIdx.y;
  int s0 = blockIdx.x * 16;
  int t = threadIdx.x;
  const float* base = Q + ((size_t)b * S_LEN + s0) * EMB + 4 * t;
  float4 acc = {0.f, 0.f, 0.f, 0.f};
#pragma unroll 4
  for (int r = 0; r < 16; r++) {
    float4 v = *(const float4*)(base + (size_t)r * EMB);
    acc.x += v.x; acc.y += v.y; acc.z += v.z; acc.w += v.w;
  }
  float* dst = xavg + b * EMB + 4 * t;
  const float inv = 1.f / (float)S_LEN;
  atomicAdd(dst + 0, acc.x * inv);
  atomicAdd(dst + 1, acc.y * inv);
  atomicAdd(dst + 2, acc.z * inv);
  atomicAdd(dst + 3, acc.w * inv);
}

// ---------------- gate = sigmoid(xavg @ Wg + bg) ----------------
__global__ __launch_bounds__(256) void gate_kernel(
    const float* __restrict__ xavg, const float* __restrict__ Wg,
    const float* __restrict__ bg, float* __restrict__ gate) {
  __shared__ float red[4][64];
  int b = blockIdx.y;
  int nl = threadIdx.x & 63;
  int n = blockIdx.x * 64 + nl;
  int kg = threadIdx.x >> 6;
  const float* xa = xavg + b * EMB;
  float s = 0.f;
#pragma unroll 4
  for (int k = kg * 256; k < kg * 256 + 256; k++)
    s += xa[k] * Wg[(size_t)k * EMB + n];
  red[kg][nl] = s;
  __syncthreads();
  if (kg == 0) {
    float tot = red[0][nl] + red[1][nl] + red[2][nl] + red[3][nl] + bg[n];
    gate[b * EMB + n] = 1.f / (1.f + __expf(-tot));
  }
}

// ---------------- pack K/V: fp32 [b,s,h*64] -> bf16 Kp[b,h,s,d], Vt[b,h,d,s] ----
__global__ __launch_bounds__(256) void pack_kv(
    const float* __restrict__ Kg, const float* __restrict__ Vg,
    __hip_bfloat16* __restrict__ Kp, __hip_bfloat16* __restrict__ Vt) {
  __shared__ short Vs[64][72];
  int s0 = blockIdx.x * 64, h = blockIdx.y, b = blockIdx.z;
  int t = threadIdx.x, r = t >> 2, c = (t & 3) * 16;
  size_t gin = ((size_t)b * S_LEN + s0 + r) * EMB + h * HD + c;
  {
    float4 a0 = *(const float4*)(Kg + gin);
    float4 a1 = *(const float4*)(Kg + gin + 4);
    float4 a2 = *(const float4*)(Kg + gin + 8);
    float4 a3 = *(const float4*)(Kg + gin + 12);
    short* kp = (short*)Kp + (((size_t)b * NH + h) * S_LEN + s0 + r) * HD + c;
    *(bf16x8*)(kp)     = pack8(a0, a1);
    *(bf16x8*)(kp + 8) = pack8(a2, a3);
  }
  {
    float4 a0 = *(const float4*)(Vg + gin);
    float4 a1 = *(const float4*)(Vg + gin + 4);
    float4 a2 = *(const float4*)(Vg + gin + 8);
    float4 a3 = *(const float4*)(Vg + gin + 12);
    *(bf16x8*)&Vs[r][c]     = pack8(a0, a1);
    *(bf16x8*)&Vs[r][c + 8] = pack8(a2, a3);
  }
  __syncthreads();
  bf16x8 o0, o1;
#pragma unroll
  for (int j = 0; j < 8; j++) o0[j] = Vs[c + j][r];
#pragma unroll
  for (int j = 0; j < 8; j++) o1[j] = Vs[c + 8 + j][r];
  short* vp = (short*)Vt + (((size_t)b * NH + h) * HD + r) * S_LEN + s0 + c;
  *(bf16x8*)(vp)     = o0;
  *(bf16x8*)(vp + 8) = o1;
}

// ---------------- causal flash attention, MFMA bf16 ----------------
__global__ __launch_bounds__(256) void flash_attn_mfma(
    const float* __restrict__ Q, const __hip_bfloat16* __restrict__ Kp,
    const __hip_bfloat16* __restrict__ Vtb, __hip_bfloat16* __restrict__ O) {
  __shared__ short Ks[64][72];
  __shared__ short Vt[64][72];
  __shared__ short Ps[4][16][72];  // bf16 P, per wave; row stride 144B (16B-mult)
  int t = threadIdx.x;
  int w = t >> 6, lane = t & 63, quad = lane >> 4, l15 = lane & 15;
  int j = blockIdx.x;
  int p = j & 255, g = j >> 8;
  int bh = p & 31, c_ = p >> 5;
  int qb = (g == 0) ? c_ : (g == 1) ? (15 - c_) : (g == 2) ? (16 + c_) : (31 - c_);
  int h = bh & 15, b = bh >> 4;
  size_t base = ((size_t)b * S_LEN) * EMB + h * HD;
  const short* kpb = (const short*)Kp + ((size_t)b * NH + h) * S_LEN * HD;
  const short* vtb = (const short*)Vtb + ((size_t)b * NH + h) * HD * S_LEN;

  // Q A-fragments, pre-scaled by 1/sqrt(HD)=0.125
  bf16x8 qf[2];
  {
    const float* qrow = Q + base + (size_t)(qb * 64 + w * 16 + l15) * EMB;
#pragma unroll
    for (int kc = 0; kc < 2; kc++) {
      float4 a = *(const float4*)(qrow + kc * 32 + quad * 8);
      float4 c = *(const float4*)(qrow + kc * 32 + quad * 8 + 4);
      a.x *= 0.125f; a.y *= 0.125f; a.z *= 0.125f; a.w *= 0.125f;
      c.x *= 0.125f; c.y *= 0.125f; c.z *= 0.125f; c.w *= 0.125f;
      qf[kc] = pack8(a, c);
    }
  }

  f32x4 acc[4];
  float lsum[4];
  f32x4 zero = {0.f, 0.f, 0.f, 0.f};
#pragma unroll
  for (int n = 0; n < 4; n++) acc[n] = zero;
#pragma unroll
  for (int r = 0; r < 4; r++) lsum[r] = 0.f;

  int r0 = t >> 2, c0 = (t & 3) * 16;
  bf16x8 kf0, kf1, vf0, vf1;  // prefetch regs
  {
    const short* kr = kpb + (size_t)r0 * HD + c0;
    kf0 = *(const bf16x8*)(kr); kf1 = *(const bf16x8*)(kr + 8);
    const short* vr = vtb + (size_t)r0 * S_LEN + c0;
    vf0 = *(const bf16x8*)(vr); vf1 = *(const bf16x8*)(vr + 8);
  }

  for (int kt = 0; kt <= qb; kt++) {
    __syncthreads();
    *(bf16x8*)&Ks[r0][c0]     = kf0;
    *(bf16x8*)&Ks[r0][c0 + 8] = kf1;
    *(bf16x8*)&Vt[r0][c0]     = vf0;
    *(bf16x8*)&Vt[r0][c0 + 8] = vf1;
    __syncthreads();
    if (kt < qb) {  // prefetch next tile during compute
      const short* kr = kpb + (size_t)((kt + 1) * 64 + r0) * HD + c0;
      kf0 = *(const bf16x8*)(kr); kf1 = *(const bf16x8*)(kr + 8);
      const short* vr = vtb + (size_t)r0 * S_LEN + (kt + 1) * 64 + c0;
      vf0 = *(const bf16x8*)(vr); vf1 = *(const bf16x8*)(vr + 8);
    }

    // S = (Q/8) K^T   (T5: boost wave priority through the MFMA cluster)
    f32x4 sc[4];
#pragma unroll
    for (int n = 0; n < 4; n++) sc[n] = zero;
    __builtin_amdgcn_s_setprio(1);
#pragma unroll
    for (int n = 0; n < 4; n++)
#pragma unroll
      for (int kc = 0; kc < 2; kc++) {
        bf16x8 kf = *(const bf16x8*)&Ks[n * 16 + l15][kc * 32 + quad * 8];
        sc[n] = __builtin_amdgcn_mfma_f32_16x16x32_bf16(qf[kc], kf, sc[n], 0, 0, 0);
      }
    __builtin_amdgcn_s_setprio(0);

    bool diag = (kt == qb);
#pragma unroll
    for (int r = 0; r < 4; r++) {
      float p0 = __expf(sc[0][r]);
      float p1 = __expf(sc[1][r]);
      float p2 = __expf(sc[2][r]);
      float p3 = __expf(sc[3][r]);
      if (diag) {
        int rowL = w * 16 + quad * 4 + r;
        if (l15      > rowL) p0 = 0.f;
        if (l15 + 16 > rowL) p1 = 0.f;
        if (l15 + 32 > rowL) p2 = 0.f;
        if (l15 + 48 > rowL) p3 = 0.f;
      }
      lsum[r] += (p0 + p1) + (p2 + p3);
      short* prow = &Ps[w][quad * 4 + r][l15];
      prow[0]  = f2bf(p0);
      prow[16] = f2bf(p1);
      prow[32] = f2bf(p2);
      prow[48] = f2bf(p3);
    }
    // drain same-wave DS writes before cross-lane reads (per-wave P region)
    asm volatile("s_waitcnt lgkmcnt(0)" ::: "memory");

    bf16x8 pf0 = *(const bf16x8*)&Ps[w][l15][quad * 8];
    bf16x8 pf1 = *(const bf16x8*)&Ps[w][l15][32 + quad * 8];
    __builtin_amdgcn_s_setprio(1);
#pragma unroll
    for (int n = 0; n < 4; n++) {
      bf16x8 vfa = *(const bf16x8*)&Vt[n * 16 + l15][quad * 8];
      acc[n] = __builtin_amdgcn_mfma_f32_16x16x32_bf16(pf0, vfa, acc[n], 0, 0, 0);
      bf16x8 vfb = *(const bf16x8*)&Vt[n * 16 + l15][32 + quad * 8];
      acc[n] = __builtin_amdgcn_mfma_f32_16x16x32_bf16(pf1, vfb, acc[n], 0, 0, 0);
    }
    __builtin_amdgcn_s_setprio(0);
  }

  // deferred row-sum: one shuffle reduction across the 16-lane row group
#pragma unroll
  for (int r = 0; r < 4; r++) {
    float l = lsum[r];
#pragma unroll
    for (int off = 1; off < 16; off <<= 1) l += __shfl_xor(l, off);
    float invl = 1.f / l;
    size_t orow = base + (size_t)(qb * 64 + w * 16 + quad * 4 + r) * EMB;
#pragma unroll
    for (int n = 0; n < 4; n++)
      O[orow + n * 16 + l15] = (__hip_bfloat16)(acc[n][r] * invl);
  }
}

// ---------------- MFMA GEMM: verified 2-phase double-buffer, BK=64 -------------
// Round-1-verified schedule (stage(kt+1) before compute(kt), one __syncthreads
// per K-tile). NEW: T1 XCD-chunked bijective blockIdx swizzle — XCD k gets a
// contiguous range of logical tiles, so co-resident blocks on one XCD share
// A-panels/B-panels in its private L2: fewer HBM misses -> FETCH drops AND the
// per-tile vmcnt drain shortens (L2 ~200cyc vs HBM ~900cyc). nwg%8==0 always.
template <int MODE, int TM>
__global__ __launch_bounds__(256) void gemm_bt(
    const __hip_bfloat16* __restrict__ A, const __hip_bfloat16* __restrict__ BT,
    int K, int N, const float* __restrict__ bias,
    const float* __restrict__ gate, const float* __restrict__ residF,
    const __hip_bfloat16* __restrict__ residB,
    float* __restrict__ outF, __hip_bfloat16* __restrict__ outB) {
  constexpr int MI = TM / 32;   // M-frags per wave
  constexpr int AR = TM / 32;   // A staging rounds (32 rows / round)
  __shared__ short As[2][TM][64];
  __shared__ short Bs[2][128][64];
  int t = threadIdx.x;
  int w = t >> 6, lane = t & 63, quad = lane >> 4, l15 = lane & 15;
  int wm = (w >> 1) * (TM / 2), wn = (w & 1) * 64;
  // T1 XCD-chunked swizzle (bijective: nwg multiple of 8)
  int nwg = gridDim.x * gridDim.y;
  int lid = blockIdx.y * gridDim.x + blockIdx.x;
  int cpx = nwg >> 3;
  int swz = (lid & 7) * cpx + (lid >> 3);
  int bx = swz % gridDim.x;
  int by = swz / gridDim.x;
  int mBase = by * TM, nBase = bx * 128;
  f32x4 acc[MI][4];
  f32x4 zero = {0.f, 0.f, 0.f, 0.f};
#pragma unroll
  for (int i = 0; i < MI; i++)
#pragma unroll
    for (int j = 0; j < 4; j++) acc[i][j] = zero;
  const short* Ag = (const short*)A;
  const short* Bg = (const short*)BT;

  int rl = t >> 3;        // 0..31 row within round
  int sck = t & 7;        // storage 16B-chunk within row
  int wrow = w << 3;      // wave's first row within round

  auto stage = [&](int buf, int kt) {
    int kb = kt << 6;
#pragma unroll
    for (int rd = 0; rd < AR; rd++) {
      int R = (rd << 5) + rl;
      gl2lds16(&Ag[(size_t)(mBase + R) * K + kb + ((sck ^ (R & 7)) << 3)],
               &As[buf][(rd << 5) + wrow][0]);
    }
#pragma unroll
    for (int rd = 0; rd < 4; rd++) {
      int R = (rd << 5) + rl;
      gl2lds16(&Bg[(size_t)(nBase + R) * K + kb + ((sck ^ (R & 7)) << 3)],
               &Bs[buf][(rd << 5) + wrow][0]);
    }
  };

  const int nt = K >> 6;
  stage(0, 0);
  __syncthreads();
  int cur = 0;
  for (int kt = 0; kt < nt; kt++) {
    if (kt + 1 < nt) stage(cur ^ 1, kt + 1);  // prefetch hides under compute
#pragma unroll
    for (int kh = 0; kh < 2; kh++) {
      bf16x8 af[MI], bfr[4];
      int dch = (kh << 2) + quad;
#pragma unroll
      for (int mi = 0; mi < MI; mi++) {
        int R = wm + mi * 16 + l15;
        af[mi] = *(const bf16x8*)&As[cur][R][(dch ^ (R & 7)) << 3];
      }
#pragma unroll
      for (int ni = 0; ni < 4; ni++) {
        int R = wn + ni * 16 + l15;
        bfr[ni] = *(const bf16x8*)&Bs[cur][R][(dch ^ (R & 7)) << 3];
      }
      __builtin_amdgcn_s_setprio(1);
#pragma unroll
      for (int mi = 0; mi < MI; mi++)
#pragma unroll
        for (int ni = 0; ni < 4; ni++)
          acc[mi][ni] = __builtin_amdgcn_mfma_f32_16x16x32_bf16(af[mi], bfr[ni], acc[mi][ni], 0, 0, 0);
      __builtin_amdgcn_s_setprio(0);
    }
    __syncthreads();
    cur ^= 1;
  }

#pragma unroll
  for (int mi = 0; mi < MI; mi++) {
#pragma unroll
    for (int r = 0; r < 4; r++) {
      int row = mBase + wm + mi * 16 + quad * 4 + r;
#pragma unroll
      for (int ni = 0; ni < 4; ni++) {
        int col = nBase + wn + ni * 16 + l15;
        float v = acc[mi][ni][r];
        if (MODE == 0) {
          float g = gate[(row >> 11) * EMB + col];
          v = g * (v + bias[col]) + residF[(size_t)row * N + col];
          outF[(size_t)row * N + col] = v;
        } else if (MODE == 1) {
          v += bias[col];
          v = 0.5f * v * (1.0f + erff(v * 0.70710678118654752f));  // exact gelu
          outB[(size_t)row * N + col] = (__hip_bfloat16)v;
        } else {
          v += bias[col] + (float)residB[(size_t)row * N + col];
          outF[(size_t)row * N + col] = v;
        }
      }
    }
  }
}

// ---------------- LayerNorm (fp32 in; bf16 or fp32 out) ----------------
__device__ __forceinline__ float block_sum_256(float v) {
  __shared__ float sb[4];
#pragma unroll
  for (int off = 32; off > 0; off >>= 1) v += __shfl_down(v, off);
  int w = threadIdx.x >> 6, ln = threadIdx.x & 63;
  if (ln == 0) sb[w] = v;
  __syncthreads();
  float r = sb[0] + sb[1] + sb[2] + sb[3];
  __syncthreads();
  return r;
}

template <bool TO_BF16>
__global__ __launch_bounds__(256) void ln_kernel(
    const float* __restrict__ y, const float* __restrict__ g,
    const float* __restrict__ b, __hip_bfloat16* __restrict__ outB,
    float* __restrict__ outF) {
  size_t row = blockIdx.x;
  const float* yr = y + row * EMB;
  float v[4];
#pragma unroll
  for (int i = 0; i < 4; i++) v[i] = yr[threadIdx.x + i * 256];
  float s = block_sum_256(v[0] + v[1] + v[2] + v[3]);
  float mu = s * (1.f / (float)EMB);
  float q = 0.f;
#pragma unroll
  for (int i = 0; i < 4; i++) { float d = v[i] - mu; q += d * d; }
  q = block_sum_256(q);
  float rs = rsqrtf(q * (1.f / (float)EMB) + 1e-5f);
#pragma unroll
  for (int i = 0; i < 4; i++) {
    int e = threadIdx.x + i * 256;
    float o = (v[i] - mu) * rs * g[e] + b[e];
    if (TO_BF16) outB[row * EMB + e] = (__hip_bfloat16)o;
    else         outF[row * EMB + e] = o;
  }
}

extern "C" void kernel_launch(void* const* d_in, const int* in_sizes, int n_in,
                              void* d_out, int out_size, void* d_ws, size_t ws_size,
                              hipStream_t stream) {
  const float* Val = (const float*)d_in[0];
  const float* Key = (const float*)d_in[1];
  const float* Qry = (const float*)d_in[2];
  const float* Wo  = (const float*)d_in[4];
  const float* bo  = (const float*)d_in[5];
  const float* Wg  = (const float*)d_in[6];
  const float* bg  = (const float*)d_in[7];
  const float* g1  = (const float*)d_in[8];
  const float* b1  = (const float*)d_in[9];
  const float* g2  = (const float*)d_in[10];
  const float* b2  = (const float*)d_in[11];
  const float* W1  = (const float*)d_in[12];
  const float* bf1 = (const float*)d_in[13];
  const float* W2  = (const float*)d_in[14];
  const float* bf2 = (const float*)d_in[15];
  float* out = (float*)d_out;

  char* ws = (char*)d_ws;
  size_t off = 0;
  auto alloc = [&](size_t bytes) {
    char* p = ws + off;
    off += (bytes + 255) & ~(size_t)255;
    return p;
  };
  const size_t MB = 1024 * 1024;
  bool bigws = ws_size >= 78 * MB;  // ws_size constant across calls

  __hip_bfloat16* WoT = (__hip_bfloat16*)alloc((size_t)EMB * EMB * 2);           // 2 MB
  __hip_bfloat16* W1T = (__hip_bfloat16*)alloc((size_t)EMB * FF_DIM * 2);        // 8 MB
  __hip_bfloat16* W2T = (__hip_bfloat16*)alloc((size_t)EMB * FF_DIM * 2);        // 8 MB
  size_t kvRegion = bigws ? (size_t)BATCH * S_LEN * FF_DIM * 2
                          : (size_t)S_LEN * FF_DIM * 2;
  char* kvBase = alloc(kvRegion);
  __hip_bfloat16* Kpk  = (__hip_bfloat16*)kvBase;                                // 8 MB
  __hip_bfloat16* Vtb  = (__hip_bfloat16*)(kvBase + 8 * MB);                     // 8 MB
  __hip_bfloat16* Hbuf = (__hip_bfloat16*)kvBase;
  __hip_bfloat16* attnO = (__hip_bfloat16*)alloc((size_t)BATCH * S_LEN * EMB * 2);// 8 MB
  float* ybuf = (float*)alloc((size_t)BATCH * S_LEN * EMB * 4);                  // 16 MB
  float* xavg = (float*)alloc(BATCH * EMB * 4);
  float* gate = (float*)alloc(BATCH * EMB * 4);
  __hip_bfloat16* xb = attnO;
  float* zbuf = ybuf;

  transpose_all<<<2304, 256, 0, stream>>>(Wo, W1, W2, WoT, W1T, W2T);
  zero_f32<<<BATCH * EMB / 256, 256, 0, stream>>>(xavg);
  xavg_partial<<<dim3(128, BATCH), 256, 0, stream>>>(Qry, xavg);
  gate_kernel<<<dim3(16, BATCH), 256, 0, stream>>>(xavg, Wg, bg, gate);
  pack_kv<<<dim3(32, NH, BATCH), 256, 0, stream>>>(Key, Val, Kpk, Vtb);
  flash_attn_mfma<<<1024, 256, 0, stream>>>(Qry, Kpk, Vtb, attnO);
  gemm_bt<0, 64><<<dim3(8, 64), 256, 0, stream>>>(attnO, WoT, EMB, EMB, bo, gate, Qry, nullptr, ybuf, nullptr);
  ln_kernel<true><<<4096, 256, 0, stream>>>(ybuf, g1, b1, xb, nullptr);
  if (bigws) {
    gemm_bt<1, 128><<<dim3(32, 32), 256, 0, stream>>>(xb, W1T, EMB, FF_DIM, bf1, nullptr, nullptr, nullptr, nullptr, Hbuf);
    gemm_bt<2, 64><<<dim3(8, 64), 256, 0, stream>>>(Hbuf, W2T, FF_DIM, EMB, bf2, nullptr, nullptr, xb, zbuf, nullptr);
  } else {
    for (int b = 0; b < BATCH; b++) {
      const __hip_bfloat16* xbb = xb + (size_t)b * S_LEN * EMB;
      gemm_bt<1, 128><<<dim3(32, 16), 256, 0, stream>>>(xbb, W1T, EMB, FF_DIM, bf1, nullptr, nullptr, nullptr, nullptr, Hbuf);
      gemm_bt<2, 64><<<dim3(8, 32), 256, 0, stream>>>(Hbuf, W2T, FF_DIM, EMB, bf2, nullptr, nullptr, xbb,
                                                      zbuf + (size_t)b * S_LEN * EMB, nullptr);
    }
  }
  ln_kernel<false><<<4096, 256, 0, stream>>>(zbuf, g2, b2, nullptr, out);
}

// Round 8
// 379.197 us; speedup vs baseline: 1.1608x; 1.0810x over previous
//
#include <hip/hip_runtime.h>
#include <hip/hip_bf16.h>

#define S_LEN 2048
#define EMB   1024
#define NH    16
#define HD    64
#define FF_DIM 4096
#define BATCH 2

typedef __attribute__((ext_vector_type(8))) short bf16x8;
typedef __attribute__((ext_vector_type(4))) float f32x4;

__device__ __forceinline__ short f2bf(float x) {
  __hip_bfloat16 h = (__hip_bfloat16)x;
  return *(short*)&h;
}
__device__ __forceinline__ bf16x8 pack8(float4 a, float4 b) {
  bf16x8 o;
  o[0] = f2bf(a.x); o[1] = f2bf(a.y); o[2] = f2bf(a.z); o[3] = f2bf(a.w);
  o[4] = f2bf(b.x); o[5] = f2bf(b.y); o[6] = f2bf(b.z); o[7] = f2bf(b.w);
  return o;
}

// async global->LDS, 16B/lane; LDS dest = wave-uniform base + lane*16
__device__ __forceinline__ void gl2lds16(const void* g, void* l) {
  __builtin_amdgcn_global_load_lds(
      (const __attribute__((address_space(1))) unsigned*)g,
      (__attribute__((address_space(3))) unsigned*)l, 16, 0, 0);
}

// ------------- fused fp32->bf16 convert+transpose for Wo, W1, W2 -------------
__device__ __forceinline__ void transpose_tile(
    const float* in, short* outS, int R, int C, int bx, int by, int t) {
  __shared__ short Ts[64][65];
  int cb = bx * 64, rb = by * 64;
  for (int idx = t; idx < 4096; idx += 256) {
    int r = idx >> 6, c = idx & 63;
    Ts[r][c] = f2bf(in[(size_t)(rb + r) * C + cb + c]);
  }
  __syncthreads();
  for (int idx = t; idx < 4096; idx += 256) {
    int oc = idx >> 6, orr = idx & 63;
    outS[(size_t)(cb + oc) * R + rb + orr] = Ts[orr][oc];
  }
}

__global__ __launch_bounds__(256) void transpose_all(
    const float* __restrict__ Wo, const float* __restrict__ W1,
    const float* __restrict__ W2, __hip_bfloat16* __restrict__ WoT,
    __hip_bfloat16* __restrict__ W1T, __hip_bfloat16* __restrict__ W2T) {
  int id = blockIdx.x, t = threadIdx.x;
  if (id < 256)        transpose_tile(Wo, (short*)WoT, EMB, EMB,    id & 15,          id >> 4,          t);
  else if (id < 1280)  transpose_tile(W1, (short*)W1T, EMB, FF_DIM, (id - 256) & 63,  (id - 256) >> 6,  t);
  else                 transpose_tile(W2, (short*)W2T, FF_DIM, EMB, (id - 1280) & 15, (id - 1280) >> 4, t);
}

// ---------------- xavg + gate accumulators: zero + atomic partial sums ---------
__global__ __launch_bounds__(256) void zero_f32(float* __restrict__ p) {
  p[blockIdx.x * 256 + threadIdx.x] = 0.f;
}

__global__ __launch_bounds__(256) void xavg_partial(
    const float* __restrict__ Q, float* __restrict__ xavg) {
  int b = blockIdx.y;
  int s0 = blockIdx.x * 16;
  int t = threadIdx.x;
  const float* base = Q + ((size_t)b * S_LEN + s0) * EMB + 4 * t;
  float4 acc = {0.f, 0.f, 0.f, 0.f};
#pragma unroll 4
  for (int r = 0; r < 16; r++) {
    float4 v = *(const float4*)(base + (size_t)r * EMB);
    acc.x += v.x; acc.y += v.y; acc.z += v.z; acc.w += v.w;
  }
  float* dst = xavg + b * EMB + 4 * t;
  const float inv = 1.f / (float)S_LEN;
  atomicAdd(dst + 0, acc.x * inv);
  atomicAdd(dst + 1, acc.y * inv);
  atomicAdd(dst + 2, acc.z * inv);
  atomicAdd(dst + 3, acc.w * inv);
}

// gacc[b][n] += sum_k xavg[b][k]*Wg[k][n] over this block's K-chunk.
// 8x more parallel than the old single-pass GEMV (256 blocks vs 32);
// sigmoid(gacc+bg) is applied in the mode0 GEMM epilogue.
__global__ __launch_bounds__(256) void gate_partial(
    const float* __restrict__ xavg, const float* __restrict__ Wg,
    float* __restrict__ gacc) {
  __shared__ float red[4][64];
  int b = blockIdx.z;
  int nl = threadIdx.x & 63;
  int n = blockIdx.x * 64 + nl;
  int kg = threadIdx.x >> 6;
  int k0 = blockIdx.y * 128 + kg * 32;
  const float* xa = xavg + b * EMB;
  float s = 0.f;
#pragma unroll 8
  for (int k = k0; k < k0 + 32; k++)
    s += xa[k] * Wg[(size_t)k * EMB + n];
  red[kg][nl] = s;
  __syncthreads();
  if (kg == 0)
    atomicAdd(&gacc[b * EMB + n], red[0][nl] + red[1][nl] + red[2][nl] + red[3][nl]);
}

// ---------------- pack K/V: fp32 [b,s,h*64] -> bf16 Kp[b,h,s,d], Vt[b,h,d,s] ----
__global__ __launch_bounds__(256) void pack_kv(
    const float* __restrict__ Kg, const float* __restrict__ Vg,
    __hip_bfloat16* __restrict__ Kp, __hip_bfloat16* __restrict__ Vt) {
  __shared__ short Vs[64][72];
  int s0 = blockIdx.x * 64, h = blockIdx.y, b = blockIdx.z;
  int t = threadIdx.x, r = t >> 2, c = (t & 3) * 16;
  size_t gin = ((size_t)b * S_LEN + s0 + r) * EMB + h * HD + c;
  {
    float4 a0 = *(const float4*)(Kg + gin);
    float4 a1 = *(const float4*)(Kg + gin + 4);
    float4 a2 = *(const float4*)(Kg + gin + 8);
    float4 a3 = *(const float4*)(Kg + gin + 12);
    short* kp = (short*)Kp + (((size_t)b * NH + h) * S_LEN + s0 + r) * HD + c;
    *(bf16x8*)(kp)     = pack8(a0, a1);
    *(bf16x8*)(kp + 8) = pack8(a2, a3);
  }
  {
    float4 a0 = *(const float4*)(Vg + gin);
    float4 a1 = *(const float4*)(Vg + gin + 4);
    float4 a2 = *(const float4*)(Vg + gin + 8);
    float4 a3 = *(const float4*)(Vg + gin + 12);
    *(bf16x8*)&Vs[r][c]     = pack8(a0, a1);
    *(bf16x8*)&Vs[r][c + 8] = pack8(a2, a3);
  }
  __syncthreads();
  bf16x8 o0, o1;
#pragma unroll
  for (int j = 0; j < 8; j++) o0[j] = Vs[c + j][r];
#pragma unroll
  for (int j = 0; j < 8; j++) o1[j] = Vs[c + 8 + j][r];
  short* vp = (short*)Vt + (((size_t)b * NH + h) * HD + r) * S_LEN + s0 + c;
  *(bf16x8*)(vp)     = o0;
  *(bf16x8*)(vp + 8) = o1;
}

// ---------------- causal flash attention, MFMA bf16 ----------------
__global__ __launch_bounds__(256) void flash_attn_mfma(
    const float* __restrict__ Q, const __hip_bfloat16* __restrict__ Kp,
    const __hip_bfloat16* __restrict__ Vtb, __hip_bfloat16* __restrict__ O) {
  __shared__ short Ks[64][72];
  __shared__ short Vt[64][72];
  __shared__ short Ps[4][16][72];  // bf16 P, per wave; row stride 144B (16B-mult)
  int t = threadIdx.x;
  int w = t >> 6, lane = t & 63, quad = lane >> 4, l15 = lane & 15;
  int j = blockIdx.x;
  int p = j & 255, g = j >> 8;
  int bh = p & 31, c_ = p >> 5;
  int qb = (g == 0) ? c_ : (g == 1) ? (15 - c_) : (g == 2) ? (16 + c_) : (31 - c_);
  int h = bh & 15, b = bh >> 4;
  size_t base = ((size_t)b * S_LEN) * EMB + h * HD;
  const short* kpb = (const short*)Kp + ((size_t)b * NH + h) * S_LEN * HD;
  const short* vtb = (const short*)Vtb + ((size_t)b * NH + h) * HD * S_LEN;

  // Q A-fragments, pre-scaled by 1/sqrt(HD)=0.125
  bf16x8 qf[2];
  {
    const float* qrow = Q + base + (size_t)(qb * 64 + w * 16 + l15) * EMB;
#pragma unroll
    for (int kc = 0; kc < 2; kc++) {
      float4 a = *(const float4*)(qrow + kc * 32 + quad * 8);
      float4 c = *(const float4*)(qrow + kc * 32 + quad * 8 + 4);
      a.x *= 0.125f; a.y *= 0.125f; a.z *= 0.125f; a.w *= 0.125f;
      c.x *= 0.125f; c.y *= 0.125f; c.z *= 0.125f; c.w *= 0.125f;
      qf[kc] = pack8(a, c);
    }
  }

  f32x4 acc[4];
  float lsum[4];
  f32x4 zero = {0.f, 0.f, 0.f, 0.f};
#pragma unroll
  for (int n = 0; n < 4; n++) acc[n] = zero;
#pragma unroll
  for (int r = 0; r < 4; r++) lsum[r] = 0.f;

  int r0 = t >> 2, c0 = (t & 3) * 16;
  bf16x8 kf0, kf1, vf0, vf1;  // prefetch regs
  {
    const short* kr = kpb + (size_t)r0 * HD + c0;
    kf0 = *(const bf16x8*)(kr); kf1 = *(const bf16x8*)(kr + 8);
    const short* vr = vtb + (size_t)r0 * S_LEN + c0;
    vf0 = *(const bf16x8*)(vr); vf1 = *(const bf16x8*)(vr + 8);
  }

  for (int kt = 0; kt <= qb; kt++) {
    __syncthreads();
    *(bf16x8*)&Ks[r0][c0]     = kf0;
    *(bf16x8*)&Ks[r0][c0 + 8] = kf1;
    *(bf16x8*)&Vt[r0][c0]     = vf0;
    *(bf16x8*)&Vt[r0][c0 + 8] = vf1;
    __syncthreads();
    if (kt < qb) {  // prefetch next tile during compute
      const short* kr = kpb + (size_t)((kt + 1) * 64 + r0) * HD + c0;
      kf0 = *(const bf16x8*)(kr); kf1 = *(const bf16x8*)(kr + 8);
      const short* vr = vtb + (size_t)r0 * S_LEN + (kt + 1) * 64 + c0;
      vf0 = *(const bf16x8*)(vr); vf1 = *(const bf16x8*)(vr + 8);
    }

    // S = (Q/8) K^T   (T5: boost wave priority through the MFMA cluster)
    f32x4 sc[4];
#pragma unroll
    for (int n = 0; n < 4; n++) sc[n] = zero;
    __builtin_amdgcn_s_setprio(1);
#pragma unroll
    for (int n = 0; n < 4; n++)
#pragma unroll
      for (int kc = 0; kc < 2; kc++) {
        bf16x8 kf = *(const bf16x8*)&Ks[n * 16 + l15][kc * 32 + quad * 8];
        sc[n] = __builtin_amdgcn_mfma_f32_16x16x32_bf16(qf[kc], kf, sc[n], 0, 0, 0);
      }
    __builtin_amdgcn_s_setprio(0);

    bool diag = (kt == qb);
#pragma unroll
    for (int r = 0; r < 4; r++) {
      float p0 = __expf(sc[0][r]);
      float p1 = __expf(sc[1][r]);
      float p2 = __expf(sc[2][r]);
      float p3 = __expf(sc[3][r]);
      if (diag) {
        int rowL = w * 16 + quad * 4 + r;
        if (l15      > rowL) p0 = 0.f;
        if (l15 + 16 > rowL) p1 = 0.f;
        if (l15 + 32 > rowL) p2 = 0.f;
        if (l15 + 48 > rowL) p3 = 0.f;
      }
      lsum[r] += (p0 + p1) + (p2 + p3);
      short* prow = &Ps[w][quad * 4 + r][l15];
      prow[0]  = f2bf(p0);
      prow[16] = f2bf(p1);
      prow[32] = f2bf(p2);
      prow[48] = f2bf(p3);
    }
    // drain same-wave DS writes before cross-lane reads (per-wave P region)
    asm volatile("s_waitcnt lgkmcnt(0)" ::: "memory");

    bf16x8 pf0 = *(const bf16x8*)&Ps[w][l15][quad * 8];
    bf16x8 pf1 = *(const bf16x8*)&Ps[w][l15][32 + quad * 8];
    __builtin_amdgcn_s_setprio(1);
#pragma unroll
    for (int n = 0; n < 4; n++) {
      bf16x8 vfa = *(const bf16x8*)&Vt[n * 16 + l15][quad * 8];
      acc[n] = __builtin_amdgcn_mfma_f32_16x16x32_bf16(pf0, vfa, acc[n], 0, 0, 0);
      bf16x8 vfb = *(const bf16x8*)&Vt[n * 16 + l15][32 + quad * 8];
      acc[n] = __builtin_amdgcn_mfma_f32_16x16x32_bf16(pf1, vfb, acc[n], 0, 0, 0);
    }
    __builtin_amdgcn_s_setprio(0);
  }

  // deferred row-sum: one shuffle reduction across the 16-lane row group
#pragma unroll
  for (int r = 0; r < 4; r++) {
    float l = lsum[r];
#pragma unroll
    for (int off = 1; off < 16; off <<= 1) l += __shfl_xor(l, off);
    float invl = 1.f / l;
    size_t orow = base + (size_t)(qb * 64 + w * 16 + quad * 4 + r) * EMB;
#pragma unroll
    for (int n = 0; n < 4; n++)
      O[orow + n * 16 + l15] = (__hip_bfloat16)(acc[n][r] * invl);
  }
}

// ---------------- MFMA GEMM: verified 2-phase double-buffer, BK=64 -------------
// SWZ: T1 XCD-chunked bijective swizzle. Round-7 A/B: helps tall-thin shapes
// (FFN2/mode0, A-panel rereads: net −6 µs) but HURTS FFN1 (FETCH 41->70 MB,
// natural round-robin already shares A-panels) — so it's per-instantiation.
// MODE 0: y = sigmoid(gacc+bg)[b][n]*(acc+bo[n]) + residF(query)  -> outF
// MODE 1: H = gelu_exact(acc + bf1[n])                            -> outB
// MODE 2: z = acc + bf2[n] + residB(x, bf16)                      -> outF
template <int MODE, int TM, bool SWZ>
__global__ __launch_bounds__(256) void gemm_bt(
    const __hip_bfloat16* __restrict__ A, const __hip_bfloat16* __restrict__ BT,
    int K, int N, const float* __restrict__ bias,
    const float* __restrict__ gate, const float* __restrict__ gbias,
    const float* __restrict__ residF, const __hip_bfloat16* __restrict__ residB,
    float* __restrict__ outF, __hip_bfloat16* __restrict__ outB) {
  constexpr int MI = TM / 32;   // M-frags per wave
  constexpr int AR = TM / 32;   // A staging rounds (32 rows / round)
  __shared__ short As[2][TM][64];
  __shared__ short Bs[2][128][64];
  int t = threadIdx.x;
  int w = t >> 6, lane = t & 63, quad = lane >> 4, l15 = lane & 15;
  int wm = (w >> 1) * (TM / 2), wn = (w & 1) * 64;
  int bx, by;
  if (SWZ) {
    int nwg = gridDim.x * gridDim.y;
    int lid = blockIdx.y * gridDim.x + blockIdx.x;
    int cpx = nwg >> 3;
    int swz = (lid & 7) * cpx + (lid >> 3);
    bx = swz % gridDim.x;
    by = swz / gridDim.x;
  } else {
    bx = blockIdx.x;
    by = blockIdx.y;
  }
  int mBase = by * TM, nBase = bx * 128;
  f32x4 acc[MI][4];
  f32x4 zero = {0.f, 0.f, 0.f, 0.f};
#pragma unroll
  for (int i = 0; i < MI; i++)
#pragma unroll
    for (int j = 0; j < 4; j++) acc[i][j] = zero;
  const short* Ag = (const short*)A;
  const short* Bg = (const short*)BT;

  int rl = t >> 3;        // 0..31 row within round
  int sck = t & 7;        // storage 16B-chunk within row
  int wrow = w << 3;      // wave's first row within round

  auto stage = [&](int buf, int kt) {
    int kb = kt << 6;
#pragma unroll
    for (int rd = 0; rd < AR; rd++) {
      int R = (rd << 5) + rl;
      gl2lds16(&Ag[(size_t)(mBase + R) * K + kb + ((sck ^ (R & 7)) << 3)],
               &As[buf][(rd << 5) + wrow][0]);
    }
#pragma unroll
    for (int rd = 0; rd < 4; rd++) {
      int R = (rd << 5) + rl;
      gl2lds16(&Bg[(size_t)(nBase + R) * K + kb + ((sck ^ (R & 7)) << 3)],
               &Bs[buf][(rd << 5) + wrow][0]);
    }
  };

  const int nt = K >> 6;
  stage(0, 0);
  __syncthreads();
  int cur = 0;
  for (int kt = 0; kt < nt; kt++) {
    if (kt + 1 < nt) stage(cur ^ 1, kt + 1);  // prefetch hides under compute
#pragma unroll
    for (int kh = 0; kh < 2; kh++) {
      bf16x8 af[MI], bfr[4];
      int dch = (kh << 2) + quad;
#pragma unroll
      for (int mi = 0; mi < MI; mi++) {
        int R = wm + mi * 16 + l15;
        af[mi] = *(const bf16x8*)&As[cur][R][(dch ^ (R & 7)) << 3];
      }
#pragma unroll
      for (int ni = 0; ni < 4; ni++) {
        int R = wn + ni * 16 + l15;
        bfr[ni] = *(const bf16x8*)&Bs[cur][R][(dch ^ (R & 7)) << 3];
      }
      __builtin_amdgcn_s_setprio(1);
#pragma unroll
      for (int mi = 0; mi < MI; mi++)
#pragma unroll
        for (int ni = 0; ni < 4; ni++)
          acc[mi][ni] = __builtin_amdgcn_mfma_f32_16x16x32_bf16(af[mi], bfr[ni], acc[mi][ni], 0, 0, 0);
      __builtin_amdgcn_s_setprio(0);
    }
    __syncthreads();
    cur ^= 1;
  }

  // MODE 0: per-column gate, uniform batch per block (TM=64 tiles never
  // straddle the S_LEN row boundary)
  float gv[4];
  if (MODE == 0) {
    int b = mBase >> 11;
#pragma unroll
    for (int ni = 0; ni < 4; ni++) {
      int col = nBase + wn + ni * 16 + l15;
      float ga = gate[b * EMB + col] + gbias[col];
      gv[ni] = 1.f / (1.f + __expf(-ga));
    }
  }

#pragma unroll
  for (int mi = 0; mi < MI; mi++) {
#pragma unroll
    for (int r = 0; r < 4; r++) {
      int row = mBase + wm + mi * 16 + quad * 4 + r;
#pragma unroll
      for (int ni = 0; ni < 4; ni++) {
        int col = nBase + wn + ni * 16 + l15;
        float v = acc[mi][ni][r];
        if (MODE == 0) {
          v = gv[ni] * (v + bias[col]) + residF[(size_t)row * N + col];
          outF[(size_t)row * N + col] = v;
        } else if (MODE == 1) {
          v += bias[col];
          v = 0.5f * v * (1.0f + erff(v * 0.70710678118654752f));  // exact gelu
          outB[(size_t)row * N + col] = (__hip_bfloat16)v;
        } else {
          v += bias[col] + (float)residB[(size_t)row * N + col];
          outF[(size_t)row * N + col] = v;
        }
      }
    }
  }
}

// ---------------- LayerNorm (fp32 in; bf16 or fp32 out) ----------------
__device__ __forceinline__ float block_sum_256(float v) {
  __shared__ float sb[4];
#pragma unroll
  for (int off = 32; off > 0; off >>= 1) v += __shfl_down(v, off);
  int w = threadIdx.x >> 6, ln = threadIdx.x & 63;
  if (ln == 0) sb[w] = v;
  __syncthreads();
  float r = sb[0] + sb[1] + sb[2] + sb[3];
  __syncthreads();
  return r;
}

template <bool TO_BF16>
__global__ __launch_bounds__(256) void ln_kernel(
    const float* __restrict__ y, const float* __restrict__ g,
    const float* __restrict__ b, __hip_bfloat16* __restrict__ outB,
    float* __restrict__ outF) {
  size_t row = blockIdx.x;
  const float* yr = y + row * EMB;
  float v[4];
#pragma unroll
  for (int i = 0; i < 4; i++) v[i] = yr[threadIdx.x + i * 256];
  float s = block_sum_256(v[0] + v[1] + v[2] + v[3]);
  float mu = s * (1.f / (float)EMB);
  float q = 0.f;
#pragma unroll
  for (int i = 0; i < 4; i++) { float d = v[i] - mu; q += d * d; }
  q = block_sum_256(q);
  float rs = rsqrtf(q * (1.f / (float)EMB) + 1e-5f);
#pragma unroll
  for (int i = 0; i < 4; i++) {
    int e = threadIdx.x + i * 256;
    float o = (v[i] - mu) * rs * g[e] + b[e];
    if (TO_BF16) outB[row * EMB + e] = (__hip_bfloat16)o;
    else         outF[row * EMB + e] = o;
  }
}

extern "C" void kernel_launch(void* const* d_in, const int* in_sizes, int n_in,
                              void* d_out, int out_size, void* d_ws, size_t ws_size,
                              hipStream_t stream) {
  const float* Val = (const float*)d_in[0];
  const float* Key = (const float*)d_in[1];
  const float* Qry = (const float*)d_in[2];
  const float* Wo  = (const float*)d_in[4];
  const float* bo  = (const float*)d_in[5];
  const float* Wg  = (const float*)d_in[6];
  const float* bg  = (const float*)d_in[7];
  const float* g1  = (const float*)d_in[8];
  const float* b1  = (const float*)d_in[9];
  const float* g2  = (const float*)d_in[10];
  const float* b2  = (const float*)d_in[11];
  const float* W1  = (const float*)d_in[12];
  const float* bf1 = (const float*)d_in[13];
  const float* W2  = (const float*)d_in[14];
  const float* bf2 = (const float*)d_in[15];
  float* out = (float*)d_out;

  char* ws = (char*)d_ws;
  size_t off = 0;
  auto alloc = [&](size_t bytes) {
    char* p = ws + off;
    off += (bytes + 255) & ~(size_t)255;
    return p;
  };
  const size_t MB = 1024 * 1024;
  bool bigws = ws_size >= 78 * MB;  // ws_size constant across calls

  __hip_bfloat16* WoT = (__hip_bfloat16*)alloc((size_t)EMB * EMB * 2);           // 2 MB
  __hip_bfloat16* W1T = (__hip_bfloat16*)alloc((size_t)EMB * FF_DIM * 2);        // 8 MB
  __hip_bfloat16* W2T = (__hip_bfloat16*)alloc((size_t)EMB * FF_DIM * 2);        // 8 MB
  size_t kvRegion = bigws ? (size_t)BATCH * S_LEN * FF_DIM * 2
                          : (size_t)S_LEN * FF_DIM * 2;
  char* kvBase = alloc(kvRegion);
  __hip_bfloat16* Kpk  = (__hip_bfloat16*)kvBase;                                // 8 MB
  __hip_bfloat16* Vtb  = (__hip_bfloat16*)(kvBase + 8 * MB);                     // 8 MB
  __hip_bfloat16* Hbuf = (__hip_bfloat16*)kvBase;
  __hip_bfloat16* attnO = (__hip_bfloat16*)alloc((size_t)BATCH * S_LEN * EMB * 2);// 8 MB
  float* ybuf = (float*)alloc((size_t)BATCH * S_LEN * EMB * 4);                  // 16 MB
  float* xavg = (float*)alloc(BATCH * EMB * 4);   // contiguous with gacc below
  float* gacc = (float*)alloc(BATCH * EMB * 4);
  __hip_bfloat16* xb = attnO;
  float* zbuf = ybuf;

  transpose_all<<<2304, 256, 0, stream>>>(Wo, W1, W2, WoT, W1T, W2T);
  // zero xavg AND gacc (contiguous, 2*BATCH*EMB floats)
  zero_f32<<<2 * BATCH * EMB / 256, 256, 0, stream>>>(xavg);
  xavg_partial<<<dim3(128, BATCH), 256, 0, stream>>>(Qry, xavg);
  gate_partial<<<dim3(16, 8, BATCH), 256, 0, stream>>>(xavg, Wg, gacc);
  pack_kv<<<dim3(32, NH, BATCH), 256, 0, stream>>>(Key, Val, Kpk, Vtb);
  flash_attn_mfma<<<1024, 256, 0, stream>>>(Qry, Kpk, Vtb, attnO);
  gemm_bt<0, 64, true><<<dim3(8, 64), 256, 0, stream>>>(attnO, WoT, EMB, EMB, bo, gacc, bg, Qry, nullptr, ybuf, nullptr);
  ln_kernel<true><<<4096, 256, 0, stream>>>(ybuf, g1, b1, xb, nullptr);
  if (bigws) {
    gemm_bt<1, 128, false><<<dim3(32, 32), 256, 0, stream>>>(xb, W1T, EMB, FF_DIM, bf1, nullptr, nullptr, nullptr, nullptr, nullptr, Hbuf);
    gemm_bt<2, 64, true><<<dim3(8, 64), 256, 0, stream>>>(Hbuf, W2T, FF_DIM, EMB, bf2, nullptr, nullptr, nullptr, xb, zbuf, nullptr);
  } else {
    for (int b = 0; b < BATCH; b++) {
      const __hip_bfloat16* xbb = xb + (size_t)b * S_LEN * EMB;
      gemm_bt<1, 128, false><<<dim3(32, 16), 256, 0, stream>>>(xbb, W1T, EMB, FF_DIM, bf1, nullptr, nullptr, nullptr, nullptr, nullptr, Hbuf);
      gemm_bt<2, 64, true><<<dim3(8, 32), 256, 0, stream>>>(Hbuf, W2T, FF_DIM, EMB, bf2, nullptr, nullptr, nullptr, xbb,
                                                            zbuf + (size_t)b * S_LEN * EMB, nullptr);
    }
  }
  ln_kernel<false><<<4096, 256, 0, stream>>>(zbuf, g2, b2, nullptr, out);
}